// Round 5
// baseline (1010.226 us; speedup 1.0000x reference)
//
#include <hip/hip_runtime.h>
#include <hip/hip_bf16.h>

#define NN 100000
#define NE 1600000
#define DIM 64
#define NG 64

#define SCAN_CHUNK 1024
#define NB_SCAN ((NN + SCAN_CHUNK - 1) / SCAN_CHUNK)

static __device__ __forceinline__ unsigned short bf16bits(float v) {
    __hip_bfloat16 b = __float2bfloat16(v);
    return *reinterpret_cast<unsigned short*>(&b);
}

// one 64-bit atomic per edge: bits 40..63 = count, bits 0..39 = sum(ew * 2^24)
__global__ void k_edge_pass(const int* __restrict__ col, const float* __restrict__ ew,
                            unsigned long long* packed, int E) {
    int e = blockIdx.x * blockDim.x + threadIdx.x;
    if (e < E) {
        unsigned int fx = (unsigned int)__float2uint_rn(ew[e] * 16777216.0f);
        unsigned long long v = (1ULL << 40) | (unsigned long long)fx;
        atomicAdd(&packed[col[e]], v);
    }
}

// decode: dinv = rsqrt(1 + fixsum*2^-24), cnt
__global__ void k_decode(const unsigned long long* __restrict__ packed,
                         float* __restrict__ dinv, int* __restrict__ cnt, int n) {
    int i = blockIdx.x * blockDim.x + threadIdx.x;
    if (i < n) {
        unsigned long long v = packed[i];
        cnt[i] = (int)(v >> 40);
        float deg = 1.0f + (float)(v & 0xFFFFFFFFFFULL) * (1.0f / 16777216.0f);
        dinv[i] = rsqrtf(deg);
    }
}

// ---------------- CSR build: scan ----------------
__global__ __launch_bounds__(256) void k_scan_reduce(const int* __restrict__ cnt,
                                                     int* __restrict__ bsum, int n) {
    __shared__ int sm[256];
    int t = threadIdx.x;
    int base = blockIdx.x * SCAN_CHUNK + t * 4;
    int s = 0;
#pragma unroll
    for (int i = 0; i < 4; ++i) {
        int idx = base + i;
        if (idx < n) s += cnt[idx];
    }
    sm[t] = s;
    __syncthreads();
    for (int off = 128; off; off >>= 1) {
        if (t < off) sm[t] += sm[t + off];
        __syncthreads();
    }
    if (t == 0) bsum[blockIdx.x] = sm[0];
}

__global__ void k_scan_bsums(int* bsum, int nb, int* rowptr, int n, int E) {
    if (threadIdx.x == 0 && blockIdx.x == 0) {
        int acc = 0;
        for (int i = 0; i < nb; ++i) {
            int v = bsum[i];
            bsum[i] = acc;
            acc += v;
        }
        rowptr[n] = E;
    }
}

__global__ __launch_bounds__(256) void k_scan_final(const int* __restrict__ cnt,
                                                    const int* __restrict__ bsum,
                                                    int* __restrict__ rowptr,
                                                    int* __restrict__ cursor, int n) {
    __shared__ int sm[256];
    int t = threadIdx.x;
    int base = blockIdx.x * SCAN_CHUNK + t * 4;
    int v[4];
    int s = 0;
#pragma unroll
    for (int i = 0; i < 4; ++i) {
        int idx = base + i;
        v[i] = (idx < n) ? cnt[idx] : 0;
        s += v[i];
    }
    sm[t] = s;
    __syncthreads();
    for (int off = 1; off < 256; off <<= 1) {
        int tmp = (t >= off) ? sm[t - off] : 0;
        __syncthreads();
        sm[t] += tmp;
        __syncthreads();
    }
    int run = bsum[blockIdx.x] + sm[t] - s;
#pragma unroll
    for (int i = 0; i < 4; ++i) {
        int idx = base + i;
        if (idx < n) {
            rowptr[idx] = run;
            cursor[idx] = run;
            run += v[i];
        }
    }
}

// csr record: .x = src row, .y = norm as float bits
__global__ void k_place(const int* __restrict__ row, const int* __restrict__ col,
                        const float* __restrict__ ew, const float* __restrict__ dinv,
                        int* cursor, int2* __restrict__ csr, int E) {
    int e = blockIdx.x * blockDim.x + threadIdx.x;
    if (e >= E) return;
    int r = row[e], c = col[e];
    int p = atomicAdd(&cursor[c], 1);
    float nm = dinv[r] * ew[e] * dinv[c];
    csr[p] = make_int2(r, __float_as_int(nm));
}

// ---------------- cast x -> bf16 ----------------
__global__ void k_cast(const float* __restrict__ x, unsigned short* __restrict__ xb, int nq) {
    int i = blockIdx.x * blockDim.x + threadIdx.x;  // one float4 each
    if (i >= nq) return;
    float4 v = ((const float4*)x)[i];
    ushort4 o;
    o.x = bf16bits(v.x);
    o.y = bf16bits(v.y);
    o.z = bf16bits(v.z);
    o.w = bf16bits(v.w);
    ((ushort4*)xb)[i] = o;
}

// ---------------- per-node gather body (lane d of the node's 64-dim row) --------
static __device__ __forceinline__ float gather_node(const int* __restrict__ rowptr,
                                                    const int2* __restrict__ csr,
                                                    const __hip_bfloat16* __restrict__ h,
                                                    const float* __restrict__ dinv,
                                                    int node, int d) {
    int e = rowptr[node], end = rowptr[node + 1];
    float di = dinv[node];
    float acc = __bfloat162float(h[(size_t)node * DIM + d]) * (di * di);
    for (; e + 8 <= end; e += 8) {
        int2 p[8];
#pragma unroll
        for (int i = 0; i < 8; ++i) p[i] = csr[e + i];
        float hv[8];
#pragma unroll
        for (int i = 0; i < 8; ++i) hv[i] = __bfloat162float(h[(size_t)p[i].x * DIM + d]);
#pragma unroll
        for (int i = 0; i < 8; ++i) acc = fmaf(hv[i], __int_as_float(p[i].y), acc);
    }
    for (; e < end; ++e) {
        int2 p = csr[e];
        acc = fmaf(__bfloat162float(h[(size_t)p.x * DIM + d]), __int_as_float(p.y), acc);
    }
    return acc;
}

// ---------------- fused gather + GEMM: out = bf16(relu((Ahat@h) @ W + b)) --------
__global__ __launch_bounds__(256) void k_gg(const int* __restrict__ rowptr,
                                            const int2* __restrict__ csr,
                                            const __hip_bfloat16* __restrict__ h,
                                            const float* __restrict__ dinv,
                                            const float* __restrict__ W,
                                            const float* __restrict__ b,
                                            __hip_bfloat16* __restrict__ out, int n) {
    __shared__ float sW[64][64];
    __shared__ float sX[16][64];
    int tid = threadIdx.x;
#pragma unroll
    for (int i = 0; i < 4; ++i) {
        int q = tid + i * 256;
        ((float4*)&sW[0][0])[q] = ((const float4*)W)[q];
    }
    int base = blockIdx.x * 16;
    int wave = tid >> 6, d = tid & 63;
    // gather phase: each wave produces 4 rows of the 16-node tile
#pragma unroll
    for (int i = 0; i < 4; ++i) {
        int r = wave * 4 + i;
        int node = base + r;
        float acc = 0.f;
        if (node < n) acc = gather_node(rowptr, csr, h, dinv, node, d);
        sX[r][d] = acc;
    }
    __syncthreads();
    // GEMM phase
    int r0 = wave * 4;
    float a0 = 0.f, a1 = 0.f, a2 = 0.f, a3 = 0.f;
#pragma unroll
    for (int k = 0; k < 64; ++k) {
        float w = sW[k][d];
        a0 = fmaf(sX[r0 + 0][k], w, a0);
        a1 = fmaf(sX[r0 + 1][k], w, a1);
        a2 = fmaf(sX[r0 + 2][k], w, a2);
        a3 = fmaf(sX[r0 + 3][k], w, a3);
    }
    float bv = b[d];
    a0 = fmaxf(a0 + bv, 0.f);
    a1 = fmaxf(a1 + bv, 0.f);
    a2 = fmaxf(a2 + bv, 0.f);
    a3 = fmaxf(a3 + bv, 0.f);
    if (base + r0 + 0 < n) out[(size_t)(base + r0 + 0) * DIM + d] = __float2bfloat16(a0);
    if (base + r0 + 1 < n) out[(size_t)(base + r0 + 1) * DIM + d] = __float2bfloat16(a1);
    if (base + r0 + 2 < n) out[(size_t)(base + r0 + 2) * DIM + d] = __float2bfloat16(a2);
    if (base + r0 + 3 < n) out[(size_t)(base + r0 + 3) * DIM + d] = __float2bfloat16(a3);
}

// ---------------- fused gather + mean-pool accumulate ----------------
#define GP_NPW 8  // consecutive nodes per wave (batch sorted -> run merge)
__global__ __launch_bounds__(256) void k_gp(const int* __restrict__ rowptr,
                                            const int2* __restrict__ csr,
                                            const __hip_bfloat16* __restrict__ h,
                                            const float* __restrict__ dinv,
                                            const int* __restrict__ batch,
                                            float* sums, float* cntf, int n) {
    int tid = threadIdx.x;
    int wave = tid >> 6, d = tid & 63;
    int node0 = (blockIdx.x * 4 + wave) * GP_NPW;
    float acc = 0.f;
    int gcur = -1, runlen = 0;
    for (int i = 0; i < GP_NPW; ++i) {
        int node = node0 + i;
        if (node >= n) break;
        int g = batch[node];
        if (g != gcur) {
            if (gcur >= 0) {
                atomicAdd(&sums[gcur * DIM + d], acc);
                if (d == 0) atomicAdd(&cntf[gcur], (float)runlen);
            }
            gcur = g;
            acc = 0.f;
            runlen = 0;
        }
        acc += gather_node(rowptr, csr, h, dinv, node, d);
        runlen++;
    }
    if (gcur >= 0) {
        atomicAdd(&sums[gcur * DIM + d], acc);
        if (d == 0) atomicAdd(&cntf[gcur], (float)runlen);
    }
}

// ---------------- head: mean -> @W2+b2 -> fc1 relu -> fc2 -> out ----------------
__global__ __launch_bounds__(64) void k_head(const float* __restrict__ sums,
                                             const float* __restrict__ cnt,
                                             const float* __restrict__ W2,
                                             const float* __restrict__ b2,
                                             const float* __restrict__ fc1w,
                                             const float* __restrict__ fc1b,
                                             const float* __restrict__ fc2w,
                                             const float* __restrict__ fc2b,
                                             const float* __restrict__ ow,
                                             const float* __restrict__ ob,
                                             float* __restrict__ out) {
    int g = blockIdx.x;
    int t = threadIdx.x;
    __shared__ float gv[64];
    __shared__ float tv[64];
    float c = fmaxf(cnt[g], 1.0f);
    gv[t] = sums[g * DIM + t] / c;
    __syncthreads();
    // layer-2 GEMM folded here: t2 = mean @ W2 + b2 (no relu)
    float acc2 = b2[t];
#pragma unroll
    for (int k = 0; k < 64; ++k) acc2 = fmaf(gv[k], W2[k * 64 + t], acc2);
    tv[t] = acc2;
    __syncthreads();
    float r = 0.0f;
    if (t < 32) {
        float acc = fc1b[t];
#pragma unroll
        for (int k = 0; k < 64; ++k) acc = fmaf(tv[k], fc1w[k * 32 + t], acc);
        acc = fmaxf(acc, 0.0f);
        r = acc * fc2w[t];
    }
#pragma unroll
    for (int off = 16; off; off >>= 1) r += __shfl_down(r, off);
    if (t == 0) out[g] = (r + fc2b[0]) * ow[0] + ob[0];
}

extern "C" void kernel_launch(void* const* d_in, const int* in_sizes, int n_in,
                              void* d_out, int out_size, void* d_ws, size_t ws_size,
                              hipStream_t stream) {
    const float* x   = (const float*)d_in[0];
    const int* eidx  = (const int*)d_in[1];
    const float* ew  = (const float*)d_in[2];
    const int* batch = (const int*)d_in[3];
    const float* W0  = (const float*)d_in[4];
    const float* b0  = (const float*)d_in[5];
    const float* W1  = (const float*)d_in[6];
    const float* b1  = (const float*)d_in[7];
    const float* W2  = (const float*)d_in[8];
    const float* b2  = (const float*)d_in[9];
    const float* fc1w = (const float*)d_in[10];
    const float* fc1b = (const float*)d_in[11];
    const float* fc2w = (const float*)d_in[12];
    const float* fc2b = (const float*)d_in[13];
    const float* ow   = (const float*)d_in[14];
    const float* ob   = (const float*)d_in[15];
    float* out = (float*)d_out;

    const int* row = eidx;
    const int* col = eidx + NE;

    // workspace layout (8B-aligned blocks first)
    char* ws = (char*)d_ws;
    unsigned long long* packed = (unsigned long long*)ws;  ws += sizeof(unsigned long long) * NN;
    int2* csr              = (int2*)ws;               ws += sizeof(int2) * NE;                 // 12.8MB
    __hip_bfloat16* Xb     = (__hip_bfloat16*)ws;     ws += sizeof(__hip_bfloat16) * (size_t)NN * DIM;  // 12.8MB
    __hip_bfloat16* Hb     = (__hip_bfloat16*)ws;     ws += sizeof(__hip_bfloat16) * (size_t)NN * DIM;  // 12.8MB
    float* dinv            = (float*)ws;              ws += sizeof(float) * NN;
    int*   cnt_i           = (int*)ws;                ws += sizeof(int) * NN;
    int*   cursor          = (int*)ws;                ws += sizeof(int) * NN;
    int*   rowptr          = (int*)ws;                ws += sizeof(int) * (NN + 1);
    int*   bsum            = (int*)ws;                ws += sizeof(int) * (NB_SCAN + 8);
    float* sums            = (float*)ws;              ws += sizeof(float) * NG * DIM;
    float* cntf            = (float*)ws;              ws += sizeof(float) * NG;

    const int TB = 256;
    int nblk_n = (NN + TB - 1) / TB;
    int nblk_e = (NE + TB - 1) / TB;

    // degree + histogram in ONE 64-bit atomic per edge
    hipMemsetAsync(packed, 0, sizeof(unsigned long long) * NN, stream);
    k_edge_pass<<<nblk_e, TB, 0, stream>>>(col, ew, packed, NE);
    k_decode<<<nblk_n, TB, 0, stream>>>(packed, dinv, cnt_i, NN);

    // CSR build
    k_scan_reduce<<<NB_SCAN, 256, 0, stream>>>(cnt_i, bsum, NN);
    k_scan_bsums<<<1, 64, 0, stream>>>(bsum, NB_SCAN, rowptr, NN, NE);
    k_scan_final<<<NB_SCAN, 256, 0, stream>>>(cnt_i, bsum, rowptr, cursor, NN);
    k_place<<<nblk_e, TB, 0, stream>>>(row, col, ew, dinv, cursor, csr, NE);

    // cast x -> bf16
    int nq = NN * DIM / 4;
    k_cast<<<(nq + TB - 1) / TB, TB, 0, stream>>>(x, (unsigned short*)Xb, nq);

    int gg_blocks = (NN + 15) / 16;
    int gp_blocks = (NN + 4 * GP_NPW - 1) / (4 * GP_NPW);

    // fused layers: h0 = relu((Ahat@x)@W0+b0); h1 = relu((Ahat@h0)@W1+b1)
    k_gg<<<gg_blocks, 256, 0, stream>>>(rowptr, csr, Xb, dinv, W0, b0, Hb, NN);
    k_gg<<<gg_blocks, 256, 0, stream>>>(rowptr, csr, Hb, dinv, W1, b1, Xb, NN);

    // fused layer-2 gather + mean-pool accumulate (W2/b2 folded into head)
    hipMemsetAsync(sums, 0, sizeof(float) * (NG * DIM + NG), stream);
    k_gp<<<gp_blocks, 256, 0, stream>>>(rowptr, csr, Xb, dinv, batch, sums, cntf, NN);
    k_head<<<NG, 64, 0, stream>>>(sums, cntf, W2, b2, fc1w, fc1b, fc2w, fc2b, ow, ob, out);
}

// Round 6
// 690.255 us; speedup vs baseline: 1.4636x; 1.4636x over previous
//
#include <hip/hip_runtime.h>
#include <hip/hip_bf16.h>

#define NN 100000
#define NE 1600000
#define DIM 64
#define NG 64

#define NBUK 3125           // NN/32 buckets, 32 nodes each
#define PERT 13             // scan elements per thread: 256*13 >= 3125

static __device__ __forceinline__ unsigned short bf16bits(float v) {
    __hip_bfloat16 b = __float2bfloat16(v);
    return *reinterpret_cast<unsigned short*>(&b);
}

// ---------------- bucket count: b = col>>5 ----------------
__global__ void k_bcount(const int* __restrict__ col, int* bcnt, int E) {
    int e = blockIdx.x * blockDim.x + threadIdx.x;
    if (e < E) atomicAdd(&bcnt[col[e] >> 5], 1);
}

// ---------------- bucket offsets scan (one block) ----------------
__global__ __launch_bounds__(256) void k_bscan(const int* __restrict__ bcnt,
                                               int* __restrict__ boff,
                                               int* __restrict__ bcur) {
    __shared__ int sm[256];
    int t = threadIdx.x;
    int base = t * PERT;
    int v[PERT];
    int s = 0;
#pragma unroll
    for (int i = 0; i < PERT; ++i) {
        int idx = base + i;
        v[i] = (idx < NBUK) ? bcnt[idx] : 0;
        s += v[i];
    }
    sm[t] = s;
    __syncthreads();
    for (int off = 1; off < 256; off <<= 1) {
        int tmp = (t >= off) ? sm[t - off] : 0;
        __syncthreads();
        sm[t] += tmp;
        __syncthreads();
    }
    int run = sm[t] - s;  // exclusive prefix
#pragma unroll
    for (int i = 0; i < PERT; ++i) {
        int idx = base + i;
        if (idx < NBUK) {
            boff[idx] = run;
            bcur[idx] = run;
            run += v[i];
        }
    }
    if (t == 255) boff[NBUK] = run;  // == NE
}

// ---------------- bin-place: binned[p] = ((cl<<20)|row, ew) ----------------
__global__ void k_binplace(const int* __restrict__ row, const int* __restrict__ col,
                           const float* __restrict__ ew, int* bcur,
                           int2* __restrict__ binned, int E) {
    int e = blockIdx.x * blockDim.x + threadIdx.x;
    if (e >= E) return;
    int c = col[e];
    int b = c >> 5, cl = c & 31;
    int p = atomicAdd(&bcur[b], 1);
    binned[p] = make_int2((cl << 20) | row[e], __float_as_int(ew[e]));
}

// ---------------- per-bucket: degree -> dinv, local scan -> rowptr ----------------
__global__ __launch_bounds__(256) void k_bdeg(const int2* __restrict__ binned,
                                              const int* __restrict__ boff,
                                              float* __restrict__ dinv,
                                              int* __restrict__ rowptr) {
    int b = blockIdx.x;
    __shared__ int lcnt[32];
    __shared__ float lsum[32];
    int t = threadIdx.x;
    if (t < 32) {
        lcnt[t] = 0;
        lsum[t] = 0.f;
    }
    __syncthreads();
    int e0 = boff[b], e1 = boff[b + 1];
    for (int e = e0 + t; e < e1; e += 256) {
        int2 v = binned[e];
        int cl = v.x >> 20;
        atomicAdd(&lcnt[cl], 1);
        atomicAdd(&lsum[cl], __int_as_float(v.y));
    }
    __syncthreads();
    if (t < 32) {
        int off = 0;
#pragma unroll
        for (int k = 0; k < 32; ++k) off += (k < t) ? lcnt[k] : 0;
        rowptr[b * 32 + t] = e0 + off;
        dinv[b * 32 + t] = rsqrtf(1.0f + lsum[t]);
    }
    if (b == 0 && t == 0) rowptr[NN] = NE;
}

// ---------------- per-bucket CSR place: csr[p] = (row, nrm) ----------------
__global__ __launch_bounds__(256) void k_bplace(const int2* __restrict__ binned,
                                                const int* __restrict__ boff,
                                                const float* __restrict__ dinv,
                                                const int* __restrict__ rowptr,
                                                int2* __restrict__ csr) {
    int b = blockIdx.x;
    __shared__ int lcur[32];
    __shared__ float ldin[32];
    int t = threadIdx.x;
    if (t < 32) {
        lcur[t] = rowptr[b * 32 + t];
        ldin[t] = dinv[b * 32 + t];
    }
    __syncthreads();
    int e0 = boff[b], e1 = boff[b + 1];
    for (int e = e0 + t; e < e1; e += 256) {
        int2 v = binned[e];
        int cl = v.x >> 20;
        int r = v.x & 0xFFFFF;
        float nm = dinv[r] * __int_as_float(v.y) * ldin[cl];
        int p = atomicAdd(&lcur[cl], 1);
        csr[p] = make_int2(r, __float_as_int(nm));
    }
}

// ---------------- cast x -> bf16 ----------------
__global__ void k_cast(const float* __restrict__ x, unsigned short* __restrict__ xb, int nq) {
    int i = blockIdx.x * blockDim.x + threadIdx.x;
    if (i >= nq) return;
    float4 v = ((const float4*)x)[i];
    ushort4 o;
    o.x = bf16bits(v.x);
    o.y = bf16bits(v.y);
    o.z = bf16bits(v.z);
    o.w = bf16bits(v.w);
    ((ushort4*)xb)[i] = o;
}

// ---------------- gather: out = h[node]*dinv^2 + sum_e h[src]*nrm (h in bf16) ----
__global__ __launch_bounds__(256) void k_gather(const int* __restrict__ rowptr,
                                                const int2* __restrict__ csr,
                                                const __hip_bfloat16* __restrict__ h,
                                                const float* __restrict__ dinv,
                                                float* __restrict__ out, int n) {
    int node = blockIdx.x * 4 + (threadIdx.x >> 6);
    if (node >= n) return;
    int d = threadIdx.x & 63;
    int e = rowptr[node], end = rowptr[node + 1];
    float di = dinv[node];
    float acc = __bfloat162float(h[(size_t)node * DIM + d]) * (di * di);
    for (; e + 8 <= end; e += 8) {
        int2 p[8];
#pragma unroll
        for (int i = 0; i < 8; ++i) p[i] = csr[e + i];
        float hv[8];
#pragma unroll
        for (int i = 0; i < 8; ++i) hv[i] = __bfloat162float(h[(size_t)p[i].x * DIM + d]);
#pragma unroll
        for (int i = 0; i < 8; ++i) acc = fmaf(hv[i], __int_as_float(p[i].y), acc);
    }
    for (; e < end; ++e) {
        int2 p = csr[e];
        acc = fmaf(__bfloat162float(h[(size_t)p.x * DIM + d]), __int_as_float(p.y), acc);
    }
    out[(size_t)node * DIM + d] = acc;
}

// ---------------- GEMM: out_bf16[n][64] = relu(in[n][64] @ W + b) ----------------
__global__ __launch_bounds__(256) void k_gemm64(const float* __restrict__ in,
                                                const float* __restrict__ W,
                                                const float* __restrict__ b,
                                                __hip_bfloat16* __restrict__ out, int n) {
    __shared__ float sW[64][64];
    __shared__ float sX[16][64];
    int tid = threadIdx.x;
#pragma unroll
    for (int i = 0; i < 4; ++i) {
        int q = tid + i * 256;
        ((float4*)&sW[0][0])[q] = ((const float4*)W)[q];
    }
    int base = blockIdx.x * 16;
    {
        int r = tid >> 4, cq = tid & 15;
        int node = base + r;
        float4 v = (node < n) ? ((const float4*)in)[(size_t)node * 16 + cq]
                              : make_float4(0.f, 0.f, 0.f, 0.f);
        ((float4*)&sX[r][0])[cq] = v;
    }
    __syncthreads();
    int d = tid & 63;
    int r0 = (tid >> 6) * 4;
    float a0 = 0.f, a1 = 0.f, a2 = 0.f, a3 = 0.f;
#pragma unroll
    for (int k = 0; k < 64; ++k) {
        float w = sW[k][d];
        a0 = fmaf(sX[r0 + 0][k], w, a0);
        a1 = fmaf(sX[r0 + 1][k], w, a1);
        a2 = fmaf(sX[r0 + 2][k], w, a2);
        a3 = fmaf(sX[r0 + 3][k], w, a3);
    }
    float bv = b[d];
    a0 = fmaxf(a0 + bv, 0.f);
    a1 = fmaxf(a1 + bv, 0.f);
    a2 = fmaxf(a2 + bv, 0.f);
    a3 = fmaxf(a3 + bv, 0.f);
    if (base + r0 + 0 < n) out[(size_t)(base + r0 + 0) * DIM + d] = __float2bfloat16(a0);
    if (base + r0 + 1 < n) out[(size_t)(base + r0 + 1) * DIM + d] = __float2bfloat16(a1);
    if (base + r0 + 2 < n) out[(size_t)(base + r0 + 2) * DIM + d] = __float2bfloat16(a2);
    if (base + r0 + 3 < n) out[(size_t)(base + r0 + 3) * DIM + d] = __float2bfloat16(a3);
}

// ---------------- pooling (batch sorted -> run-length partial sums) ----------
#define PCH 256
__global__ __launch_bounds__(256) void k_pool(const int* __restrict__ batch,
                                              const float* __restrict__ h,
                                              float* sums, float* cnt, int n) {
    int t = threadIdx.x;
    int d = t & 63, s = t >> 6;
    int base = blockIdx.x * PCH;
    float acc = 0.f;
    int gcur = -1, cntv = 0;
    for (int i = s; i < PCH; i += 4) {
        int node = base + i;
        if (node >= n) break;
        int g = batch[node];
        if (g != gcur) {
            if (gcur >= 0) {
                atomicAdd(&sums[gcur * DIM + d], acc);
                if (d == 0) atomicAdd(&cnt[gcur], (float)cntv);
            }
            gcur = g;
            acc = 0.f;
            cntv = 0;
        }
        acc += h[(size_t)node * DIM + d];
        cntv++;
    }
    if (gcur >= 0) {
        atomicAdd(&sums[gcur * DIM + d], acc);
        if (d == 0) atomicAdd(&cnt[gcur], (float)cntv);
    }
}

// ---------------- head: mean -> @W2+b2 -> fc1 relu -> fc2 -> out ----------------
__global__ __launch_bounds__(64) void k_head(const float* __restrict__ sums,
                                             const float* __restrict__ cnt,
                                             const float* __restrict__ W2,
                                             const float* __restrict__ b2,
                                             const float* __restrict__ fc1w,
                                             const float* __restrict__ fc1b,
                                             const float* __restrict__ fc2w,
                                             const float* __restrict__ fc2b,
                                             const float* __restrict__ ow,
                                             const float* __restrict__ ob,
                                             float* __restrict__ out) {
    int g = blockIdx.x;
    int t = threadIdx.x;
    __shared__ float gv[64];
    __shared__ float tv[64];
    float c = fmaxf(cnt[g], 1.0f);
    gv[t] = sums[g * DIM + t] / c;
    __syncthreads();
    float acc2 = b2[t];
#pragma unroll
    for (int k = 0; k < 64; ++k) acc2 = fmaf(gv[k], W2[k * 64 + t], acc2);
    tv[t] = acc2;
    __syncthreads();
    float r = 0.0f;
    if (t < 32) {
        float acc = fc1b[t];
#pragma unroll
        for (int k = 0; k < 64; ++k) acc = fmaf(tv[k], fc1w[k * 32 + t], acc);
        acc = fmaxf(acc, 0.0f);
        r = acc * fc2w[t];
    }
#pragma unroll
    for (int off = 16; off; off >>= 1) r += __shfl_down(r, off);
    if (t == 0) out[g] = (r + fc2b[0]) * ow[0] + ob[0];
}

extern "C" void kernel_launch(void* const* d_in, const int* in_sizes, int n_in,
                              void* d_out, int out_size, void* d_ws, size_t ws_size,
                              hipStream_t stream) {
    const float* x   = (const float*)d_in[0];
    const int* eidx  = (const int*)d_in[1];
    const float* ew  = (const float*)d_in[2];
    const int* batch = (const int*)d_in[3];
    const float* W0  = (const float*)d_in[4];
    const float* b0  = (const float*)d_in[5];
    const float* W1  = (const float*)d_in[6];
    const float* b1  = (const float*)d_in[7];
    const float* W2  = (const float*)d_in[8];
    const float* b2  = (const float*)d_in[9];
    const float* fc1w = (const float*)d_in[10];
    const float* fc1b = (const float*)d_in[11];
    const float* fc2w = (const float*)d_in[12];
    const float* fc2b = (const float*)d_in[13];
    const float* ow   = (const float*)d_in[14];
    const float* ob   = (const float*)d_in[15];
    float* out = (float*)d_out;

    const int* row = eidx;
    const int* col = eidx + NE;

    // workspace layout (8B-aligned blocks first)
    char* ws = (char*)d_ws;
    int2* binned           = (int2*)ws;               ws += sizeof(int2) * NE;                 // 12.8MB
    int2* csr              = (int2*)ws;               ws += sizeof(int2) * NE;                 // 12.8MB
    __hip_bfloat16* Xb     = (__hip_bfloat16*)ws;     ws += sizeof(__hip_bfloat16) * (size_t)NN * DIM;
    __hip_bfloat16* Hb     = (__hip_bfloat16*)ws;     ws += sizeof(__hip_bfloat16) * (size_t)NN * DIM;
    float* G               = (float*)ws;              ws += sizeof(float) * (size_t)NN * DIM;  // 25.6MB
    float* dinv            = (float*)ws;              ws += sizeof(float) * NN;
    int*   rowptr          = (int*)ws;                ws += sizeof(int) * (NN + 1);
    int*   bcnt            = (int*)ws;                ws += sizeof(int) * (NBUK + 1);
    int*   boff            = (int*)ws;                ws += sizeof(int) * (NBUK + 1);
    int*   bcur            = (int*)ws;                ws += sizeof(int) * (NBUK + 1);
    float* sums            = (float*)ws;              ws += sizeof(float) * NG * DIM;
    float* cntf            = (float*)ws;              ws += sizeof(float) * NG;

    const int TB = 256;
    int nblk_e = (NE + TB - 1) / TB;

    // ---- CSR build via col-range bucketing (no global scatter thrash) ----
    hipMemsetAsync(bcnt, 0, sizeof(int) * NBUK, stream);
    k_bcount<<<nblk_e, TB, 0, stream>>>(col, bcnt, NE);
    k_bscan<<<1, 256, 0, stream>>>(bcnt, boff, bcur);
    k_binplace<<<nblk_e, TB, 0, stream>>>(row, col, ew, bcur, binned, NE);
    k_bdeg<<<NBUK, 256, 0, stream>>>(binned, boff, dinv, rowptr);
    k_bplace<<<NBUK, 256, 0, stream>>>(binned, boff, dinv, rowptr, csr);

    // cast x -> bf16
    int nq = NN * DIM / 4;
    k_cast<<<(nq + TB - 1) / TB, TB, 0, stream>>>(x, (unsigned short*)Xb, nq);

    int gemm_blocks = (NN + 15) / 16;
    int gath_blocks = (NN + 3) / 4;

    // gather-first layers: g = Ahat@X ; X' = relu(g @ W + b)
    k_gather<<<gath_blocks, 256, 0, stream>>>(rowptr, csr, Xb, dinv, G, NN);
    k_gemm64<<<gemm_blocks, 256, 0, stream>>>(G, W0, b0, Hb, NN);
    k_gather<<<gath_blocks, 256, 0, stream>>>(rowptr, csr, Hb, dinv, G, NN);
    k_gemm64<<<gemm_blocks, 256, 0, stream>>>(G, W1, b1, Xb, NN);
    k_gather<<<gath_blocks, 256, 0, stream>>>(rowptr, csr, Xb, dinv, G, NN);

    // pool over final gather; W2/b2 folded into head
    hipMemsetAsync(sums, 0, sizeof(float) * (NG * DIM + NG), stream);
    k_pool<<<(NN + PCH - 1) / PCH, 256, 0, stream>>>(batch, G, sums, cntf, NN);
    k_head<<<NG, 64, 0, stream>>>(sums, cntf, W2, b2, fc1w, fc1b, fc2w, fc2b, ow, ob, out);
}

// Round 7
// 453.666 us; speedup vs baseline: 2.2268x; 1.5215x over previous
//
#include <hip/hip_runtime.h>
#include <hip/hip_bf16.h>

#define NN 100000
#define NE 1600000
#define DIM 64
#define NG 64

#define NBUK 391      // coarse buckets of 256 nodes: bucket = col >> 8
#define EPB 4096      // edges per pass-1 block

static __device__ __forceinline__ unsigned short bf16bits(float v) {
    __hip_bfloat16 b = __float2bfloat16(v);
    return *reinterpret_cast<unsigned short*>(&b);
}

// ---------------- global bucket histogram (LDS-aggregated) ----------------
__global__ __launch_bounds__(256) void k_ghist(const int* __restrict__ col,
                                               int* gcnt, int E) {
    __shared__ int hist[NBUK];
    int t = threadIdx.x;
    for (int i = t; i < NBUK; i += 256) hist[i] = 0;
    __syncthreads();
    int e0 = blockIdx.x * EPB, e1 = min(e0 + EPB, E);
    for (int e = e0 + t; e < e1; e += 256) atomicAdd(&hist[col[e] >> 8], 1);
    __syncthreads();
    for (int i = t; i < NBUK; i += 256)
        if (hist[i]) atomicAdd(&gcnt[i], hist[i]);
}

// ---------------- bucket offsets scan (one block, 2 elems/thread) ----------------
__global__ __launch_bounds__(256) void k_gscan(const int* __restrict__ gcnt,
                                               int* __restrict__ boff,
                                               int* __restrict__ bcur) {
    __shared__ int sm[256];
    int t = threadIdx.x;
    int v0 = (2 * t < NBUK) ? gcnt[2 * t] : 0;
    int v1 = (2 * t + 1 < NBUK) ? gcnt[2 * t + 1] : 0;
    int s = v0 + v1;
    sm[t] = s;
    __syncthreads();
    for (int off = 1; off < 256; off <<= 1) {
        int tmp = (t >= off) ? sm[t - off] : 0;
        __syncthreads();
        sm[t] += tmp;
        __syncthreads();
    }
    int run = sm[t] - s;
    if (2 * t < NBUK) { boff[2 * t] = run; bcur[2 * t] = run; }
    run += v0;
    if (2 * t + 1 < NBUK) { boff[2 * t + 1] = run; bcur[2 * t + 1] = run; }
    if (t == 255) boff[NBUK] = run + v1;  // == NE
}

// ---------------- pass 1: block-local counting sort into bucket ranges ----------
// binned record: .x = (cl<<17)|row  (cl = col&255, row<2^17), .y = ew bits
__global__ __launch_bounds__(256) void k_part1(const int* __restrict__ row,
                                               const int* __restrict__ col,
                                               const float* __restrict__ ew,
                                               int* bcur, int2* __restrict__ binned,
                                               int E) {
    __shared__ int hist[NBUK];
    __shared__ int base_s[NBUK];
    int t = threadIdx.x;
    for (int i = t; i < NBUK; i += 256) hist[i] = 0;
    __syncthreads();
    int e0 = blockIdx.x * EPB, e1 = min(e0 + EPB, E);
    for (int e = e0 + t; e < e1; e += 256) atomicAdd(&hist[col[e] >> 8], 1);
    __syncthreads();
    // one global atomic per nonzero bucket reserves a block-private contiguous range
    for (int i = t; i < NBUK; i += 256) {
        int c = hist[i];
        base_s[i] = c ? atomicAdd(&bcur[i], c) : 0;
        hist[i] = 0;  // reuse as local cursor
    }
    __syncthreads();
    for (int e = e0 + t; e < e1; e += 256) {
        int c = col[e];
        int b = c >> 8, cl = c & 255;
        int rk = atomicAdd(&hist[b], 1);
        binned[base_s[b] + rk] = make_int2((cl << 17) | row[e], __float_as_int(ew[e]));
    }
}

// ---------------- pass 2a: per-bucket degree (fixed-point) + rowptr + dinv --------
__global__ __launch_bounds__(256) void k_p2a(const int2* __restrict__ binned,
                                             const int* __restrict__ boff,
                                             float* __restrict__ dinv,
                                             int* __restrict__ rowptr) {
    int b = blockIdx.x, t = threadIdx.x;
    __shared__ unsigned int dsum[256];
    __shared__ int ncnt[256];
    __shared__ int sm[256];
    dsum[t] = 0;
    ncnt[t] = 0;
    __syncthreads();
    int e0 = boff[b], e1 = boff[b + 1];
    for (int e = e0 + t; e < e1; e += 256) {
        int2 v = binned[e];
        int cl = v.x >> 17;
        atomicAdd(&ncnt[cl], 1);
        unsigned int fx = (unsigned int)__float2uint_rn(__int_as_float(v.y) * 16777216.0f);
        atomicAdd(&dsum[cl], fx);
    }
    __syncthreads();
    int c = ncnt[t];
    sm[t] = c;
    __syncthreads();
    for (int off = 1; off < 256; off <<= 1) {
        int tmp = (t >= off) ? sm[t - off] : 0;
        __syncthreads();
        sm[t] += tmp;
        __syncthreads();
    }
    int node = b * 256 + t;
    if (node < NN) {
        rowptr[node] = e0 + sm[t] - c;
        dinv[node] = rsqrtf(1.0f + (float)dsum[t] * (1.0f / 16777216.0f));
    }
    if (b == 0 && t == 0) rowptr[NN] = NE;
}

// ---------------- pass 2b: per-bucket CSR place (contiguous window) ----------------
__global__ __launch_bounds__(256) void k_p2b(const int2* __restrict__ binned,
                                             const int* __restrict__ boff,
                                             const float* __restrict__ dinv,
                                             const int* __restrict__ rowptr,
                                             int2* __restrict__ csr) {
    int b = blockIdx.x, t = threadIdx.x;
    __shared__ int ncur[256];
    __shared__ float ldin[256];
    int node = b * 256 + t;
    ncur[t] = (node < NN) ? rowptr[node] : 0;
    ldin[t] = (node < NN) ? dinv[node] : 0.f;
    __syncthreads();
    int e0 = boff[b], e1 = boff[b + 1];
    for (int e = e0 + t; e < e1; e += 256) {
        int2 v = binned[e];
        int cl = v.x >> 17, r = v.x & 0x1FFFF;
        float nm = dinv[r] * __int_as_float(v.y) * ldin[cl];
        int p = atomicAdd(&ncur[cl], 1);
        csr[p] = make_int2(r, __float_as_int(nm));
    }
}

// ---------------- cast x -> bf16 ----------------
__global__ void k_cast(const float* __restrict__ x, unsigned short* __restrict__ xb, int nq) {
    int i = blockIdx.x * blockDim.x + threadIdx.x;
    if (i >= nq) return;
    float4 v = ((const float4*)x)[i];
    ushort4 o;
    o.x = bf16bits(v.x);
    o.y = bf16bits(v.y);
    o.z = bf16bits(v.z);
    o.w = bf16bits(v.w);
    ((ushort4*)xb)[i] = o;
}

// ---------------- gather: out = h[node]*dinv^2 + sum_e h[src]*nrm (h in bf16) ----
__global__ __launch_bounds__(256) void k_gather(const int* __restrict__ rowptr,
                                                const int2* __restrict__ csr,
                                                const __hip_bfloat16* __restrict__ h,
                                                const float* __restrict__ dinv,
                                                float* __restrict__ out, int n) {
    int node = blockIdx.x * 4 + (threadIdx.x >> 6);
    if (node >= n) return;
    int d = threadIdx.x & 63;
    int e = rowptr[node], end = rowptr[node + 1];
    float di = dinv[node];
    float acc = __bfloat162float(h[(size_t)node * DIM + d]) * (di * di);
    for (; e + 8 <= end; e += 8) {
        int2 p[8];
#pragma unroll
        for (int i = 0; i < 8; ++i) p[i] = csr[e + i];
        float hv[8];
#pragma unroll
        for (int i = 0; i < 8; ++i) hv[i] = __bfloat162float(h[(size_t)p[i].x * DIM + d]);
#pragma unroll
        for (int i = 0; i < 8; ++i) acc = fmaf(hv[i], __int_as_float(p[i].y), acc);
    }
    for (; e < end; ++e) {
        int2 p = csr[e];
        acc = fmaf(__bfloat162float(h[(size_t)p.x * DIM + d]), __int_as_float(p.y), acc);
    }
    out[(size_t)node * DIM + d] = acc;
}

// ---------------- GEMM: out_bf16[n][64] = relu(in[n][64] @ W + b) ----------------
__global__ __launch_bounds__(256) void k_gemm64(const float* __restrict__ in,
                                                const float* __restrict__ W,
                                                const float* __restrict__ b,
                                                __hip_bfloat16* __restrict__ out, int n) {
    __shared__ float sW[64][64];
    __shared__ float sX[16][64];
    int tid = threadIdx.x;
#pragma unroll
    for (int i = 0; i < 4; ++i) {
        int q = tid + i * 256;
        ((float4*)&sW[0][0])[q] = ((const float4*)W)[q];
    }
    int base = blockIdx.x * 16;
    {
        int r = tid >> 4, cq = tid & 15;
        int node = base + r;
        float4 v = (node < n) ? ((const float4*)in)[(size_t)node * 16 + cq]
                              : make_float4(0.f, 0.f, 0.f, 0.f);
        ((float4*)&sX[r][0])[cq] = v;
    }
    __syncthreads();
    int d = tid & 63;
    int r0 = (tid >> 6) * 4;
    float a0 = 0.f, a1 = 0.f, a2 = 0.f, a3 = 0.f;
#pragma unroll
    for (int k = 0; k < 64; ++k) {
        float w = sW[k][d];
        a0 = fmaf(sX[r0 + 0][k], w, a0);
        a1 = fmaf(sX[r0 + 1][k], w, a1);
        a2 = fmaf(sX[r0 + 2][k], w, a2);
        a3 = fmaf(sX[r0 + 3][k], w, a3);
    }
    float bv = b[d];
    a0 = fmaxf(a0 + bv, 0.f);
    a1 = fmaxf(a1 + bv, 0.f);
    a2 = fmaxf(a2 + bv, 0.f);
    a3 = fmaxf(a3 + bv, 0.f);
    if (base + r0 + 0 < n) out[(size_t)(base + r0 + 0) * DIM + d] = __float2bfloat16(a0);
    if (base + r0 + 1 < n) out[(size_t)(base + r0 + 1) * DIM + d] = __float2bfloat16(a1);
    if (base + r0 + 2 < n) out[(size_t)(base + r0 + 2) * DIM + d] = __float2bfloat16(a2);
    if (base + r0 + 3 < n) out[(size_t)(base + r0 + 3) * DIM + d] = __float2bfloat16(a3);
}

// ---------------- pooling (batch sorted -> run-length partial sums) ----------
#define PCH 256
__global__ __launch_bounds__(256) void k_pool(const int* __restrict__ batch,
                                              const float* __restrict__ h,
                                              float* sums, float* cnt, int n) {
    int t = threadIdx.x;
    int d = t & 63, s = t >> 6;
    int base = blockIdx.x * PCH;
    float acc = 0.f;
    int gcur = -1, cntv = 0;
    for (int i = s; i < PCH; i += 4) {
        int node = base + i;
        if (node >= n) break;
        int g = batch[node];
        if (g != gcur) {
            if (gcur >= 0) {
                atomicAdd(&sums[gcur * DIM + d], acc);
                if (d == 0) atomicAdd(&cnt[gcur], (float)cntv);
            }
            gcur = g;
            acc = 0.f;
            cntv = 0;
        }
        acc += h[(size_t)node * DIM + d];
        cntv++;
    }
    if (gcur >= 0) {
        atomicAdd(&sums[gcur * DIM + d], acc);
        if (d == 0) atomicAdd(&cnt[gcur], (float)cntv);
    }
}

// ---------------- head: mean -> @W2+b2 -> fc1 relu -> fc2 -> out ----------------
__global__ __launch_bounds__(64) void k_head(const float* __restrict__ sums,
                                             const float* __restrict__ cnt,
                                             const float* __restrict__ W2,
                                             const float* __restrict__ b2,
                                             const float* __restrict__ fc1w,
                                             const float* __restrict__ fc1b,
                                             const float* __restrict__ fc2w,
                                             const float* __restrict__ fc2b,
                                             const float* __restrict__ ow,
                                             const float* __restrict__ ob,
                                             float* __restrict__ out) {
    int g = blockIdx.x;
    int t = threadIdx.x;
    __shared__ float gv[64];
    __shared__ float tv[64];
    float c = fmaxf(cnt[g], 1.0f);
    gv[t] = sums[g * DIM + t] / c;
    __syncthreads();
    float acc2 = b2[t];
#pragma unroll
    for (int k = 0; k < 64; ++k) acc2 = fmaf(gv[k], W2[k * 64 + t], acc2);
    tv[t] = acc2;
    __syncthreads();
    float r = 0.0f;
    if (t < 32) {
        float acc = fc1b[t];
#pragma unroll
        for (int k = 0; k < 64; ++k) acc = fmaf(tv[k], fc1w[k * 32 + t], acc);
        acc = fmaxf(acc, 0.0f);
        r = acc * fc2w[t];
    }
#pragma unroll
    for (int off = 16; off; off >>= 1) r += __shfl_down(r, off);
    if (t == 0) out[g] = (r + fc2b[0]) * ow[0] + ob[0];
}

extern "C" void kernel_launch(void* const* d_in, const int* in_sizes, int n_in,
                              void* d_out, int out_size, void* d_ws, size_t ws_size,
                              hipStream_t stream) {
    const float* x   = (const float*)d_in[0];
    const int* eidx  = (const int*)d_in[1];
    const float* ew  = (const float*)d_in[2];
    const int* batch = (const int*)d_in[3];
    const float* W0  = (const float*)d_in[4];
    const float* b0  = (const float*)d_in[5];
    const float* W1  = (const float*)d_in[6];
    const float* b1  = (const float*)d_in[7];
    const float* W2  = (const float*)d_in[8];
    const float* b2  = (const float*)d_in[9];
    const float* fc1w = (const float*)d_in[10];
    const float* fc1b = (const float*)d_in[11];
    const float* fc2w = (const float*)d_in[12];
    const float* fc2b = (const float*)d_in[13];
    const float* ow   = (const float*)d_in[14];
    const float* ob   = (const float*)d_in[15];
    float* out = (float*)d_out;

    const int* row = eidx;
    const int* col = eidx + NE;

    // workspace layout (8B-aligned blocks first)
    char* ws = (char*)d_ws;
    int2* binned           = (int2*)ws;               ws += sizeof(int2) * NE;                 // 12.8MB
    int2* csr              = (int2*)ws;               ws += sizeof(int2) * NE;                 // 12.8MB
    __hip_bfloat16* Xb     = (__hip_bfloat16*)ws;     ws += sizeof(__hip_bfloat16) * (size_t)NN * DIM;
    __hip_bfloat16* Hb     = (__hip_bfloat16*)ws;     ws += sizeof(__hip_bfloat16) * (size_t)NN * DIM;
    float* G               = (float*)ws;              ws += sizeof(float) * (size_t)NN * DIM;  // 25.6MB
    float* dinv            = (float*)ws;              ws += sizeof(float) * NN;
    int*   rowptr          = (int*)ws;                ws += sizeof(int) * (NN + 1);
    int*   gcnt            = (int*)ws;                ws += sizeof(int) * (NBUK + 1);
    int*   boff            = (int*)ws;                ws += sizeof(int) * (NBUK + 1);
    int*   bcur            = (int*)ws;                ws += sizeof(int) * (NBUK + 1);
    float* sums            = (float*)ws;              ws += sizeof(float) * NG * DIM;
    float* cntf            = (float*)ws;              ws += sizeof(float) * NG;

    const int TB = 256;
    int p1_blocks = (NE + EPB - 1) / EPB;  // 391

    // ---- CSR build: block-private bucket reservations (write-merge friendly) ----
    hipMemsetAsync(gcnt, 0, sizeof(int) * NBUK, stream);
    k_ghist<<<p1_blocks, TB, 0, stream>>>(col, gcnt, NE);
    k_gscan<<<1, 256, 0, stream>>>(gcnt, boff, bcur);
    k_part1<<<p1_blocks, TB, 0, stream>>>(row, col, ew, bcur, binned, NE);
    k_p2a<<<NBUK, 256, 0, stream>>>(binned, boff, dinv, rowptr);
    k_p2b<<<NBUK, 256, 0, stream>>>(binned, boff, dinv, rowptr, csr);

    // cast x -> bf16
    int nq = NN * DIM / 4;
    k_cast<<<(nq + TB - 1) / TB, TB, 0, stream>>>(x, (unsigned short*)Xb, nq);

    int gemm_blocks = (NN + 15) / 16;
    int gath_blocks = (NN + 3) / 4;

    // gather-first layers: g = Ahat@X ; X' = relu(g @ W + b)
    k_gather<<<gath_blocks, 256, 0, stream>>>(rowptr, csr, Xb, dinv, G, NN);
    k_gemm64<<<gemm_blocks, 256, 0, stream>>>(G, W0, b0, Hb, NN);
    k_gather<<<gath_blocks, 256, 0, stream>>>(rowptr, csr, Hb, dinv, G, NN);
    k_gemm64<<<gemm_blocks, 256, 0, stream>>>(G, W1, b1, Xb, NN);
    k_gather<<<gath_blocks, 256, 0, stream>>>(rowptr, csr, Xb, dinv, G, NN);

    // pool over final gather; W2/b2 folded into head
    hipMemsetAsync(sums, 0, sizeof(float) * (NG * DIM + NG), stream);
    k_pool<<<(NN + PCH - 1) / PCH, 256, 0, stream>>>(batch, G, sums, cntf, NN);
    k_head<<<NG, 64, 0, stream>>>(sums, cntf, W2, b2, fc1w, fc1b, fc2w, fc2b, ow, ob, out);
}

// Round 8
// 411.706 us; speedup vs baseline: 2.4538x; 1.1019x over previous
//
#include <hip/hip_runtime.h>
#include <hip/hip_bf16.h>

#define NN 100000
#define NE 1600000
#define DIM 64
#define NG 64

#define NBUK 391      // coarse buckets of 256 nodes: bucket = col >> 8
#define EPB 4096      // edges per pass-1 block

static __device__ __forceinline__ unsigned short bf16bits(float v) {
    __hip_bfloat16 b = __float2bfloat16(v);
    return *reinterpret_cast<unsigned short*>(&b);
}
static __device__ __forceinline__ float bfbits2f(unsigned short u) {
    unsigned int x = ((unsigned int)u) << 16;
    return __uint_as_float(x);
}

// ---------------- global bucket histogram (LDS-aggregated) ----------------
__global__ __launch_bounds__(256) void k_ghist(const int* __restrict__ col,
                                               int* gcnt, int E) {
    __shared__ int hist[NBUK];
    int t = threadIdx.x;
    for (int i = t; i < NBUK; i += 256) hist[i] = 0;
    __syncthreads();
    int e0 = blockIdx.x * EPB, e1 = min(e0 + EPB, E);
    for (int e = e0 + t; e < e1; e += 256) atomicAdd(&hist[col[e] >> 8], 1);
    __syncthreads();
    for (int i = t; i < NBUK; i += 256)
        if (hist[i]) atomicAdd(&gcnt[i], hist[i]);
}

// ---------------- bucket offsets scan (one block, 2 elems/thread) ----------------
__global__ __launch_bounds__(256) void k_gscan(const int* __restrict__ gcnt,
                                               int* __restrict__ boff,
                                               int* __restrict__ bcur) {
    __shared__ int sm[256];
    int t = threadIdx.x;
    int v0 = (2 * t < NBUK) ? gcnt[2 * t] : 0;
    int v1 = (2 * t + 1 < NBUK) ? gcnt[2 * t + 1] : 0;
    int s = v0 + v1;
    sm[t] = s;
    __syncthreads();
    for (int off = 1; off < 256; off <<= 1) {
        int tmp = (t >= off) ? sm[t - off] : 0;
        __syncthreads();
        sm[t] += tmp;
        __syncthreads();
    }
    int run = sm[t] - s;
    if (2 * t < NBUK) { boff[2 * t] = run; bcur[2 * t] = run; }
    run += v0;
    if (2 * t + 1 < NBUK) { boff[2 * t + 1] = run; bcur[2 * t + 1] = run; }
    if (t == 255) boff[NBUK] = run + v1;  // == NE
}

// ---------------- pass 1: block-local counting sort into bucket ranges ----------
// binned record: .x = (cl<<17)|row  (cl = col&255, row<2^17), .y = ew bits
__global__ __launch_bounds__(256) void k_part1(const int* __restrict__ row,
                                               const int* __restrict__ col,
                                               const float* __restrict__ ew,
                                               int* bcur, int2* __restrict__ binned,
                                               int E) {
    __shared__ int hist[NBUK];
    __shared__ int base_s[NBUK];
    int t = threadIdx.x;
    for (int i = t; i < NBUK; i += 256) hist[i] = 0;
    __syncthreads();
    int e0 = blockIdx.x * EPB, e1 = min(e0 + EPB, E);
    for (int e = e0 + t; e < e1; e += 256) atomicAdd(&hist[col[e] >> 8], 1);
    __syncthreads();
    for (int i = t; i < NBUK; i += 256) {
        int c = hist[i];
        base_s[i] = c ? atomicAdd(&bcur[i], c) : 0;
        hist[i] = 0;  // reuse as local cursor
    }
    __syncthreads();
    for (int e = e0 + t; e < e1; e += 256) {
        int c = col[e];
        int b = c >> 8, cl = c & 255;
        int rk = atomicAdd(&hist[b], 1);
        binned[base_s[b] + rk] = make_int2((cl << 17) | row[e], __float_as_int(ew[e]));
    }
}

// ---------------- pass 2a: per-bucket degree (fixed-point) + rowptr + dinv --------
__global__ __launch_bounds__(256) void k_p2a(const int2* __restrict__ binned,
                                             const int* __restrict__ boff,
                                             float* __restrict__ dinv,
                                             int* __restrict__ rowptr) {
    int b = blockIdx.x, t = threadIdx.x;
    __shared__ unsigned int dsum[256];
    __shared__ int ncnt[256];
    __shared__ int sm[256];
    dsum[t] = 0;
    ncnt[t] = 0;
    __syncthreads();
    int e0 = boff[b], e1 = boff[b + 1];
    for (int e = e0 + t; e < e1; e += 256) {
        int2 v = binned[e];
        int cl = v.x >> 17;
        atomicAdd(&ncnt[cl], 1);
        unsigned int fx = (unsigned int)__float2uint_rn(__int_as_float(v.y) * 16777216.0f);
        atomicAdd(&dsum[cl], fx);
    }
    __syncthreads();
    int c = ncnt[t];
    sm[t] = c;
    __syncthreads();
    for (int off = 1; off < 256; off <<= 1) {
        int tmp = (t >= off) ? sm[t - off] : 0;
        __syncthreads();
        sm[t] += tmp;
        __syncthreads();
    }
    int node = b * 256 + t;
    if (node < NN) {
        rowptr[node] = e0 + sm[t] - c;
        dinv[node] = rsqrtf(1.0f + (float)dsum[t] * (1.0f / 16777216.0f));
    }
    if (b == 0 && t == 0) rowptr[NN] = NE;
}

// ---------------- pass 2b: per-bucket CSR place (contiguous window) ----------------
__global__ __launch_bounds__(256) void k_p2b(const int2* __restrict__ binned,
                                             const int* __restrict__ boff,
                                             const float* __restrict__ dinv,
                                             const int* __restrict__ rowptr,
                                             int2* __restrict__ csr) {
    int b = blockIdx.x, t = threadIdx.x;
    __shared__ int ncur[256];
    __shared__ float ldin[256];
    int node = b * 256 + t;
    ncur[t] = (node < NN) ? rowptr[node] : 0;
    ldin[t] = (node < NN) ? dinv[node] : 0.f;
    __syncthreads();
    int e0 = boff[b], e1 = boff[b + 1];
    for (int e = e0 + t; e < e1; e += 256) {
        int2 v = binned[e];
        int cl = v.x >> 17, r = v.x & 0x1FFFF;
        float nm = dinv[r] * __int_as_float(v.y) * ldin[cl];
        int p = atomicAdd(&ncur[cl], 1);
        csr[p] = make_int2(r, __float_as_int(nm));
    }
}

// ---------------- cast x -> bf16 ----------------
__global__ void k_cast(const float* __restrict__ x, unsigned short* __restrict__ xb, int nq) {
    int i = blockIdx.x * blockDim.x + threadIdx.x;
    if (i >= nq) return;
    float4 v = ((const float4*)x)[i];
    ushort4 o;
    o.x = bf16bits(v.x);
    o.y = bf16bits(v.y);
    o.z = bf16bits(v.z);
    o.w = bf16bits(v.w);
    ((ushort4*)xb)[i] = o;
}

// ---------------- gather v2: 16 lanes x 8B per row, 4 edges per wave-instr -------
// lane = (g = l>>4, sub = l&15); group g walks edges e0+g, e0+g+4, ...
// acc = float4 over dims [sub*4, sub*4+4); cross-group merge via shfl_xor.
template <bool F32OUT>
__global__ __launch_bounds__(256) void k_gather2(const int* __restrict__ rowptr,
                                                 const int2* __restrict__ csr,
                                                 const __hip_bfloat16* __restrict__ h,
                                                 const float* __restrict__ dinv,
                                                 void* __restrict__ out, int n) {
    int node = blockIdx.x * 4 + (threadIdx.x >> 6);
    if (node >= n) return;
    int l = threadIdx.x & 63;
    int g = l >> 4, sub = l & 15;
    const ushort4* h4 = (const ushort4*)h;  // row r -> h4[r*16 + sub]
    float4 acc = make_float4(0.f, 0.f, 0.f, 0.f);
    if (g == 0) {  // self-loop term
        float di = dinv[node];
        float s = di * di;
        ushort4 v = h4[(size_t)node * 16 + sub];
        acc.x = bfbits2f(v.x) * s;
        acc.y = bfbits2f(v.y) * s;
        acc.z = bfbits2f(v.z) * s;
        acc.w = bfbits2f(v.w) * s;
    }
    int e = rowptr[node] + g, e1 = rowptr[node + 1];
    for (; e + 4 < e1; e += 8) {  // unroll 2: two rows in flight
        int2 p0 = csr[e];
        int2 p1 = csr[e + 4];
        ushort4 r0 = h4[(size_t)p0.x * 16 + sub];
        ushort4 r1 = h4[(size_t)p1.x * 16 + sub];
        float n0 = __int_as_float(p0.y), n1 = __int_as_float(p1.y);
        acc.x = fmaf(bfbits2f(r0.x), n0, acc.x);
        acc.y = fmaf(bfbits2f(r0.y), n0, acc.y);
        acc.z = fmaf(bfbits2f(r0.z), n0, acc.z);
        acc.w = fmaf(bfbits2f(r0.w), n0, acc.w);
        acc.x = fmaf(bfbits2f(r1.x), n1, acc.x);
        acc.y = fmaf(bfbits2f(r1.y), n1, acc.y);
        acc.z = fmaf(bfbits2f(r1.z), n1, acc.z);
        acc.w = fmaf(bfbits2f(r1.w), n1, acc.w);
    }
    if (e < e1) {
        int2 p = csr[e];
        ushort4 r = h4[(size_t)p.x * 16 + sub];
        float nm = __int_as_float(p.y);
        acc.x = fmaf(bfbits2f(r.x), nm, acc.x);
        acc.y = fmaf(bfbits2f(r.y), nm, acc.y);
        acc.z = fmaf(bfbits2f(r.z), nm, acc.z);
        acc.w = fmaf(bfbits2f(r.w), nm, acc.w);
    }
    // merge the 4 groups (lanes converged here)
#pragma unroll
    for (int off = 16; off <= 32; off <<= 1) {
        acc.x += __shfl_xor(acc.x, off);
        acc.y += __shfl_xor(acc.y, off);
        acc.z += __shfl_xor(acc.z, off);
        acc.w += __shfl_xor(acc.w, off);
    }
    if (g == 0) {
        if (F32OUT) {
            ((float4*)out)[(size_t)node * 16 + sub] = acc;
        } else {
            ushort4 o;
            o.x = bf16bits(acc.x);
            o.y = bf16bits(acc.y);
            o.z = bf16bits(acc.z);
            o.w = bf16bits(acc.w);
            ((ushort4*)out)[(size_t)node * 16 + sub] = o;
        }
    }
}

// ---------------- GEMM (bf16 in): out_bf16 = relu(in[n][64] @ W + b) ----------------
__global__ __launch_bounds__(256) void k_gemm64b(const __hip_bfloat16* __restrict__ in,
                                                 const float* __restrict__ W,
                                                 const float* __restrict__ b,
                                                 __hip_bfloat16* __restrict__ out, int n) {
    __shared__ float sW[64][64];
    __shared__ float sX[16][64];
    int tid = threadIdx.x;
#pragma unroll
    for (int i = 0; i < 4; ++i) {
        int q = tid + i * 256;
        ((float4*)&sW[0][0])[q] = ((const float4*)W)[q];
    }
    int base = blockIdx.x * 16;
    {
        int r = tid >> 4, q = tid & 15;  // 16 ushort4 per row
        int node = base + r;
        float4 f = make_float4(0.f, 0.f, 0.f, 0.f);
        if (node < n) {
            ushort4 v = ((const ushort4*)in)[(size_t)node * 16 + q];
            f.x = bfbits2f(v.x);
            f.y = bfbits2f(v.y);
            f.z = bfbits2f(v.z);
            f.w = bfbits2f(v.w);
        }
        ((float4*)&sX[r][0])[q] = f;
    }
    __syncthreads();
    int d = tid & 63;
    int r0 = (tid >> 6) * 4;
    float a0 = 0.f, a1 = 0.f, a2 = 0.f, a3 = 0.f;
#pragma unroll
    for (int k = 0; k < 64; ++k) {
        float w = sW[k][d];
        a0 = fmaf(sX[r0 + 0][k], w, a0);
        a1 = fmaf(sX[r0 + 1][k], w, a1);
        a2 = fmaf(sX[r0 + 2][k], w, a2);
        a3 = fmaf(sX[r0 + 3][k], w, a3);
    }
    float bv = b[d];
    a0 = fmaxf(a0 + bv, 0.f);
    a1 = fmaxf(a1 + bv, 0.f);
    a2 = fmaxf(a2 + bv, 0.f);
    a3 = fmaxf(a3 + bv, 0.f);
    if (base + r0 + 0 < n) out[(size_t)(base + r0 + 0) * DIM + d] = __float2bfloat16(a0);
    if (base + r0 + 1 < n) out[(size_t)(base + r0 + 1) * DIM + d] = __float2bfloat16(a1);
    if (base + r0 + 2 < n) out[(size_t)(base + r0 + 2) * DIM + d] = __float2bfloat16(a2);
    if (base + r0 + 3 < n) out[(size_t)(base + r0 + 3) * DIM + d] = __float2bfloat16(a3);
}

// ---------------- pooling (batch sorted -> run-length partial sums) ----------
#define PCH 256
__global__ __launch_bounds__(256) void k_pool(const int* __restrict__ batch,
                                              const float* __restrict__ h,
                                              float* sums, float* cnt, int n) {
    int t = threadIdx.x;
    int d = t & 63, s = t >> 6;
    int base = blockIdx.x * PCH;
    float acc = 0.f;
    int gcur = -1, cntv = 0;
    for (int i = s; i < PCH; i += 4) {
        int node = base + i;
        if (node >= n) break;
        int g = batch[node];
        if (g != gcur) {
            if (gcur >= 0) {
                atomicAdd(&sums[gcur * DIM + d], acc);
                if (d == 0) atomicAdd(&cnt[gcur], (float)cntv);
            }
            gcur = g;
            acc = 0.f;
            cntv = 0;
        }
        acc += h[(size_t)node * DIM + d];
        cntv++;
    }
    if (gcur >= 0) {
        atomicAdd(&sums[gcur * DIM + d], acc);
        if (d == 0) atomicAdd(&cnt[gcur], (float)cntv);
    }
}

// ---------------- head: mean -> @W2+b2 -> fc1 relu -> fc2 -> out ----------------
__global__ __launch_bounds__(64) void k_head(const float* __restrict__ sums,
                                             const float* __restrict__ cnt,
                                             const float* __restrict__ W2,
                                             const float* __restrict__ b2,
                                             const float* __restrict__ fc1w,
                                             const float* __restrict__ fc1b,
                                             const float* __restrict__ fc2w,
                                             const float* __restrict__ fc2b,
                                             const float* __restrict__ ow,
                                             const float* __restrict__ ob,
                                             float* __restrict__ out) {
    int g = blockIdx.x;
    int t = threadIdx.x;
    __shared__ float gv[64];
    __shared__ float tv[64];
    float c = fmaxf(cnt[g], 1.0f);
    gv[t] = sums[g * DIM + t] / c;
    __syncthreads();
    float acc2 = b2[t];
#pragma unroll
    for (int k = 0; k < 64; ++k) acc2 = fmaf(gv[k], W2[k * 64 + t], acc2);
    tv[t] = acc2;
    __syncthreads();
    float r = 0.0f;
    if (t < 32) {
        float acc = fc1b[t];
#pragma unroll
        for (int k = 0; k < 64; ++k) acc = fmaf(tv[k], fc1w[k * 32 + t], acc);
        acc = fmaxf(acc, 0.0f);
        r = acc * fc2w[t];
    }
#pragma unroll
    for (int off = 16; off; off >>= 1) r += __shfl_down(r, off);
    if (t == 0) out[g] = (r + fc2b[0]) * ow[0] + ob[0];
}

extern "C" void kernel_launch(void* const* d_in, const int* in_sizes, int n_in,
                              void* d_out, int out_size, void* d_ws, size_t ws_size,
                              hipStream_t stream) {
    const float* x   = (const float*)d_in[0];
    const int* eidx  = (const int*)d_in[1];
    const float* ew  = (const float*)d_in[2];
    const int* batch = (const int*)d_in[3];
    const float* W0  = (const float*)d_in[4];
    const float* b0  = (const float*)d_in[5];
    const float* W1  = (const float*)d_in[6];
    const float* b1  = (const float*)d_in[7];
    const float* W2  = (const float*)d_in[8];
    const float* b2  = (const float*)d_in[9];
    const float* fc1w = (const float*)d_in[10];
    const float* fc1b = (const float*)d_in[11];
    const float* fc2w = (const float*)d_in[12];
    const float* fc2b = (const float*)d_in[13];
    const float* ow   = (const float*)d_in[14];
    const float* ob   = (const float*)d_in[15];
    float* out = (float*)d_out;

    const int* row = eidx;
    const int* col = eidx + NE;

    // workspace layout (8B-aligned blocks first)
    char* ws = (char*)d_ws;
    int2* binned           = (int2*)ws;               ws += sizeof(int2) * NE;                 // 12.8MB
    int2* csr              = (int2*)ws;               ws += sizeof(int2) * NE;                 // 12.8MB
    __hip_bfloat16* Xb     = (__hip_bfloat16*)ws;     ws += sizeof(__hip_bfloat16) * (size_t)NN * DIM;
    __hip_bfloat16* Hb     = (__hip_bfloat16*)ws;     ws += sizeof(__hip_bfloat16) * (size_t)NN * DIM;
    float* G               = (float*)ws;              ws += sizeof(float) * (size_t)NN * DIM;  // 25.6MB
    float* dinv            = (float*)ws;              ws += sizeof(float) * NN;
    int*   rowptr          = (int*)ws;                ws += sizeof(int) * (NN + 1);
    int*   gcnt            = (int*)ws;                ws += sizeof(int) * (NBUK + 1);
    int*   boff            = (int*)ws;                ws += sizeof(int) * (NBUK + 1);
    int*   bcur            = (int*)ws;                ws += sizeof(int) * (NBUK + 1);
    float* sums            = (float*)ws;              ws += sizeof(float) * NG * DIM;
    float* cntf            = (float*)ws;              ws += sizeof(float) * NG;

    const int TB = 256;
    int p1_blocks = (NE + EPB - 1) / EPB;  // 391

    // ---- CSR build: block-private bucket reservations (write-merge friendly) ----
    hipMemsetAsync(gcnt, 0, sizeof(int) * NBUK, stream);
    k_ghist<<<p1_blocks, TB, 0, stream>>>(col, gcnt, NE);
    k_gscan<<<1, 256, 0, stream>>>(gcnt, boff, bcur);
    k_part1<<<p1_blocks, TB, 0, stream>>>(row, col, ew, bcur, binned, NE);
    k_p2a<<<NBUK, 256, 0, stream>>>(binned, boff, dinv, rowptr);
    k_p2b<<<NBUK, 256, 0, stream>>>(binned, boff, dinv, rowptr, csr);

    // cast x -> bf16
    int nq = NN * DIM / 4;
    k_cast<<<(nq + TB - 1) / TB, TB, 0, stream>>>(x, (unsigned short*)Xb, nq);

    int gemm_blocks = (NN + 15) / 16;
    int gath_blocks = (NN + 3) / 4;

    // gather-first layers (bf16 pipeline): g = Ahat@X ; X' = relu(g @ W + b)
    k_gather2<false><<<gath_blocks, 256, 0, stream>>>(rowptr, csr, Xb, dinv, Hb, NN);
    k_gemm64b<<<gemm_blocks, 256, 0, stream>>>(Hb, W0, b0, Xb, NN);
    k_gather2<false><<<gath_blocks, 256, 0, stream>>>(rowptr, csr, Xb, dinv, Hb, NN);
    k_gemm64b<<<gemm_blocks, 256, 0, stream>>>(Hb, W1, b1, Xb, NN);
    k_gather2<true><<<gath_blocks, 256, 0, stream>>>(rowptr, csr, Xb, dinv, G, NN);

    // pool over final gather; W2/b2 folded into head
    hipMemsetAsync(sums, 0, sizeof(float) * (NG * DIM + NG), stream);
    k_pool<<<(NN + PCH - 1) / PCH, 256, 0, stream>>>(batch, G, sums, cntf, NN);
    k_head<<<NG, 64, 0, stream>>>(sums, cntf, W2, b2, fc1w, fc1b, fc2w, fc2b, ow, ob, out);
}

// Round 9
// 383.027 us; speedup vs baseline: 2.6375x; 1.0749x over previous
//
#include <hip/hip_runtime.h>
#include <hip/hip_bf16.h>

#define NN 100000
#define NE 1600000
#define DIM 64
#define NG 64

#define NBUK 391      // coarse buckets of 256 nodes: bucket = col >> 8
#define EPB 4096      // edges per pass-1 block

static __device__ __forceinline__ unsigned short bf16bits(float v) {
    __hip_bfloat16 b = __float2bfloat16(v);
    return *reinterpret_cast<unsigned short*>(&b);
}
static __device__ __forceinline__ float bfbits2f(unsigned short u) {
    unsigned int x = ((unsigned int)u) << 16;
    return __uint_as_float(x);
}

// ---------------- global bucket histogram (LDS-aggregated) ----------------
__global__ __launch_bounds__(256) void k_ghist(const int* __restrict__ col,
                                               int* gcnt, int E) {
    __shared__ int hist[NBUK];
    int t = threadIdx.x;
    for (int i = t; i < NBUK; i += 256) hist[i] = 0;
    __syncthreads();
    int e0 = blockIdx.x * EPB, e1 = min(e0 + EPB, E);
    for (int e = e0 + t; e < e1; e += 256) atomicAdd(&hist[col[e] >> 8], 1);
    __syncthreads();
    for (int i = t; i < NBUK; i += 256)
        if (hist[i]) atomicAdd(&gcnt[i], hist[i]);
}

// ---------------- bucket offsets scan (one block, 2 elems/thread) ----------------
__global__ __launch_bounds__(256) void k_gscan(const int* __restrict__ gcnt,
                                               int* __restrict__ boff,
                                               int* __restrict__ bcur) {
    __shared__ int sm[256];
    int t = threadIdx.x;
    int v0 = (2 * t < NBUK) ? gcnt[2 * t] : 0;
    int v1 = (2 * t + 1 < NBUK) ? gcnt[2 * t + 1] : 0;
    int s = v0 + v1;
    sm[t] = s;
    __syncthreads();
    for (int off = 1; off < 256; off <<= 1) {
        int tmp = (t >= off) ? sm[t - off] : 0;
        __syncthreads();
        sm[t] += tmp;
        __syncthreads();
    }
    int run = sm[t] - s;
    if (2 * t < NBUK) { boff[2 * t] = run; bcur[2 * t] = run; }
    run += v0;
    if (2 * t + 1 < NBUK) { boff[2 * t + 1] = run; bcur[2 * t + 1] = run; }
    if (t == 255) boff[NBUK] = run + v1;  // == NE
}

// ---------------- pass 1: block-local counting sort into bucket ranges ----------
// binned record: .x = (cl<<17)|row  (cl = col&255, row<2^17), .y = ew bits
__global__ __launch_bounds__(256) void k_part1(const int* __restrict__ row,
                                               const int* __restrict__ col,
                                               const float* __restrict__ ew,
                                               int* bcur, int2* __restrict__ binned,
                                               int E) {
    __shared__ int hist[NBUK];
    __shared__ int base_s[NBUK];
    int t = threadIdx.x;
    for (int i = t; i < NBUK; i += 256) hist[i] = 0;
    __syncthreads();
    int e0 = blockIdx.x * EPB, e1 = min(e0 + EPB, E);
    for (int e = e0 + t; e < e1; e += 256) atomicAdd(&hist[col[e] >> 8], 1);
    __syncthreads();
    for (int i = t; i < NBUK; i += 256) {
        int c = hist[i];
        base_s[i] = c ? atomicAdd(&bcur[i], c) : 0;
        hist[i] = 0;  // reuse as local cursor
    }
    __syncthreads();
    for (int e = e0 + t; e < e1; e += 256) {
        int c = col[e];
        int b = c >> 8, cl = c & 255;
        int rk = atomicAdd(&hist[b], 1);
        binned[base_s[b] + rk] = make_int2((cl << 17) | row[e], __float_as_int(ew[e]));
    }
}

// ---------------- pass 2a: per-bucket degree (fixed-point) + rowptr + dinv --------
__global__ __launch_bounds__(256) void k_p2a(const int2* __restrict__ binned,
                                             const int* __restrict__ boff,
                                             float* __restrict__ dinv,
                                             int* __restrict__ rowptr) {
    int b = blockIdx.x, t = threadIdx.x;
    __shared__ unsigned int dsum[256];
    __shared__ int ncnt[256];
    __shared__ int sm[256];
    dsum[t] = 0;
    ncnt[t] = 0;
    __syncthreads();
    int e0 = boff[b], e1 = boff[b + 1];
    for (int e = e0 + t; e < e1; e += 256) {
        int2 v = binned[e];
        int cl = v.x >> 17;
        atomicAdd(&ncnt[cl], 1);
        unsigned int fx = (unsigned int)__float2uint_rn(__int_as_float(v.y) * 16777216.0f);
        atomicAdd(&dsum[cl], fx);
    }
    __syncthreads();
    int c = ncnt[t];
    sm[t] = c;
    __syncthreads();
    for (int off = 1; off < 256; off <<= 1) {
        int tmp = (t >= off) ? sm[t - off] : 0;
        __syncthreads();
        sm[t] += tmp;
        __syncthreads();
    }
    int node = b * 256 + t;
    if (node < NN) {
        rowptr[node] = e0 + sm[t] - c;
        dinv[node] = rsqrtf(1.0f + (float)dsum[t] * (1.0f / 16777216.0f));
    }
    if (b == 0 && t == 0) rowptr[NN] = NE;
}

// ---------------- pass 2b: per-bucket CSR place (contiguous window) ----------------
__global__ __launch_bounds__(256) void k_p2b(const int2* __restrict__ binned,
                                             const int* __restrict__ boff,
                                             const float* __restrict__ dinv,
                                             const int* __restrict__ rowptr,
                                             int2* __restrict__ csr) {
    int b = blockIdx.x, t = threadIdx.x;
    __shared__ int ncur[256];
    __shared__ float ldin[256];
    int node = b * 256 + t;
    ncur[t] = (node < NN) ? rowptr[node] : 0;
    ldin[t] = (node < NN) ? dinv[node] : 0.f;
    __syncthreads();
    int e0 = boff[b], e1 = boff[b + 1];
    for (int e = e0 + t; e < e1; e += 256) {
        int2 v = binned[e];
        int cl = v.x >> 17, r = v.x & 0x1FFFF;
        float nm = dinv[r] * __int_as_float(v.y) * ldin[cl];
        int p = atomicAdd(&ncur[cl], 1);
        csr[p] = make_int2(r, __float_as_int(nm));
    }
}

// ---------------- cast x -> bf16 ----------------
__global__ void k_cast(const float* __restrict__ x, unsigned short* __restrict__ xb, int nq) {
    int i = blockIdx.x * blockDim.x + threadIdx.x;
    if (i >= nq) return;
    float4 v = ((const float4*)x)[i];
    ushort4 o;
    o.x = bf16bits(v.x);
    o.y = bf16bits(v.y);
    o.z = bf16bits(v.z);
    o.w = bf16bits(v.w);
    ((ushort4*)xb)[i] = o;
}

// ---------------- gather v2: 16 lanes x 8B per row, 4 edges per wave-instr -------
template <bool F32OUT>
__global__ __launch_bounds__(256) void k_gather2(const int* __restrict__ rowptr,
                                                 const int2* __restrict__ csr,
                                                 const __hip_bfloat16* __restrict__ h,
                                                 const float* __restrict__ dinv,
                                                 void* __restrict__ out, int n) {
    int node = blockIdx.x * 4 + (threadIdx.x >> 6);
    if (node >= n) return;
    int l = threadIdx.x & 63;
    int g = l >> 4, sub = l & 15;
    const ushort4* h4 = (const ushort4*)h;  // row r -> h4[r*16 + sub]
    float4 acc = make_float4(0.f, 0.f, 0.f, 0.f);
    if (g == 0) {  // self-loop term
        float di = dinv[node];
        float s = di * di;
        ushort4 v = h4[(size_t)node * 16 + sub];
        acc.x = bfbits2f(v.x) * s;
        acc.y = bfbits2f(v.y) * s;
        acc.z = bfbits2f(v.z) * s;
        acc.w = bfbits2f(v.w) * s;
    }
    int e = rowptr[node] + g, e1 = rowptr[node + 1];
    for (; e + 4 < e1; e += 8) {  // unroll 2: two rows in flight
        int2 p0 = csr[e];
        int2 p1 = csr[e + 4];
        ushort4 r0 = h4[(size_t)p0.x * 16 + sub];
        ushort4 r1 = h4[(size_t)p1.x * 16 + sub];
        float n0 = __int_as_float(p0.y), n1 = __int_as_float(p1.y);
        acc.x = fmaf(bfbits2f(r0.x), n0, acc.x);
        acc.y = fmaf(bfbits2f(r0.y), n0, acc.y);
        acc.z = fmaf(bfbits2f(r0.z), n0, acc.z);
        acc.w = fmaf(bfbits2f(r0.w), n0, acc.w);
        acc.x = fmaf(bfbits2f(r1.x), n1, acc.x);
        acc.y = fmaf(bfbits2f(r1.y), n1, acc.y);
        acc.z = fmaf(bfbits2f(r1.z), n1, acc.z);
        acc.w = fmaf(bfbits2f(r1.w), n1, acc.w);
    }
    if (e < e1) {
        int2 p = csr[e];
        ushort4 r = h4[(size_t)p.x * 16 + sub];
        float nm = __int_as_float(p.y);
        acc.x = fmaf(bfbits2f(r.x), nm, acc.x);
        acc.y = fmaf(bfbits2f(r.y), nm, acc.y);
        acc.z = fmaf(bfbits2f(r.z), nm, acc.z);
        acc.w = fmaf(bfbits2f(r.w), nm, acc.w);
    }
#pragma unroll
    for (int off = 16; off <= 32; off <<= 1) {
        acc.x += __shfl_xor(acc.x, off);
        acc.y += __shfl_xor(acc.y, off);
        acc.z += __shfl_xor(acc.z, off);
        acc.w += __shfl_xor(acc.w, off);
    }
    if (g == 0) {
        if (F32OUT) {
            ((float4*)out)[(size_t)node * 16 + sub] = acc;
        } else {
            ushort4 o;
            o.x = bf16bits(acc.x);
            o.y = bf16bits(acc.y);
            o.z = bf16bits(acc.z);
            o.w = bf16bits(acc.w);
            ((ushort4*)out)[(size_t)node * 16 + sub] = o;
        }
    }
}

// ---------------- GEMM v2: 64-node tile, 4x4 register tile, float4 LDS reads ------
// out_bf16[n][64] = relu(in_bf16[n][64] @ W + b)
__global__ __launch_bounds__(256) void k_gemm64v2(const ushort4* __restrict__ in,
                                                  const float* __restrict__ W,
                                                  const float* __restrict__ b,
                                                  ushort4* __restrict__ out, int n) {
    __shared__ float sW[64][64];   // [k][d]
    __shared__ float sX[64][68];   // [node][k], +4 pad: 16B-aligned rows, 2-way banks
    int tid = threadIdx.x;
    // stage W: 1024 float4, 4/thread
#pragma unroll
    for (int i = 0; i < 4; ++i) {
        int q = tid + i * 256;
        ((float4*)&sW[0][0])[q] = ((const float4*)W)[q];
    }
    int base = blockIdx.x * 64;
    // stage X: 64 rows x 16 ushort4 -> f32, 4/thread
#pragma unroll
    for (int i = 0; i < 4; ++i) {
        int idx = tid + i * 256;  // 0..1023
        int r = idx >> 4, q = idx & 15;
        int node = base + r;
        float4 f = make_float4(0.f, 0.f, 0.f, 0.f);
        if (node < n) {
            ushort4 v = in[(size_t)node * 16 + q];
            f.x = bfbits2f(v.x);
            f.y = bfbits2f(v.y);
            f.z = bfbits2f(v.z);
            f.w = bfbits2f(v.w);
        }
        *(float4*)&sX[r][q * 4] = f;
    }
    __syncthreads();
    int ng = tid >> 4;  // node group: rows ng*4 .. ng*4+3
    int dg = tid & 15;  // dim group:  cols dg*4 .. dg*4+3
    float acc[4][4];
#pragma unroll
    for (int i = 0; i < 4; ++i)
#pragma unroll
        for (int j = 0; j < 4; ++j) acc[i][j] = 0.f;
#pragma unroll
    for (int k4 = 0; k4 < 16; ++k4) {
        float4 xr[4];
#pragma unroll
        for (int i = 0; i < 4; ++i) xr[i] = *(const float4*)&sX[ng * 4 + i][k4 * 4];
        float4 wc[4];
#pragma unroll
        for (int j = 0; j < 4; ++j) wc[j] = *(const float4*)&sW[k4 * 4 + j][dg * 4];
#pragma unroll
        for (int i = 0; i < 4; ++i) {
            acc[i][0] = fmaf(xr[i].x, wc[0].x, acc[i][0]);
            acc[i][1] = fmaf(xr[i].x, wc[0].y, acc[i][1]);
            acc[i][2] = fmaf(xr[i].x, wc[0].z, acc[i][2]);
            acc[i][3] = fmaf(xr[i].x, wc[0].w, acc[i][3]);
            acc[i][0] = fmaf(xr[i].y, wc[1].x, acc[i][0]);
            acc[i][1] = fmaf(xr[i].y, wc[1].y, acc[i][1]);
            acc[i][2] = fmaf(xr[i].y, wc[1].z, acc[i][2]);
            acc[i][3] = fmaf(xr[i].y, wc[1].w, acc[i][3]);
            acc[i][0] = fmaf(xr[i].z, wc[2].x, acc[i][0]);
            acc[i][1] = fmaf(xr[i].z, wc[2].y, acc[i][1]);
            acc[i][2] = fmaf(xr[i].z, wc[2].z, acc[i][2]);
            acc[i][3] = fmaf(xr[i].z, wc[2].w, acc[i][3]);
            acc[i][0] = fmaf(xr[i].w, wc[3].x, acc[i][0]);
            acc[i][1] = fmaf(xr[i].w, wc[3].y, acc[i][1]);
            acc[i][2] = fmaf(xr[i].w, wc[3].z, acc[i][2]);
            acc[i][3] = fmaf(xr[i].w, wc[3].w, acc[i][3]);
        }
    }
    float4 bv = ((const float4*)b)[dg];
#pragma unroll
    for (int i = 0; i < 4; ++i) {
        int node = base + ng * 4 + i;
        if (node < n) {
            ushort4 o;
            o.x = bf16bits(fmaxf(acc[i][0] + bv.x, 0.f));
            o.y = bf16bits(fmaxf(acc[i][1] + bv.y, 0.f));
            o.z = bf16bits(fmaxf(acc[i][2] + bv.z, 0.f));
            o.w = bf16bits(fmaxf(acc[i][3] + bv.w, 0.f));
            out[(size_t)node * 16 + dg] = o;
        }
    }
}

// ---------------- pooling (batch sorted -> run-length partial sums) ----------
#define PCH 256
__global__ __launch_bounds__(256) void k_pool(const int* __restrict__ batch,
                                              const float* __restrict__ h,
                                              float* sums, float* cnt, int n) {
    int t = threadIdx.x;
    int d = t & 63, s = t >> 6;
    int base = blockIdx.x * PCH;
    float acc = 0.f;
    int gcur = -1, cntv = 0;
    for (int i = s; i < PCH; i += 4) {
        int node = base + i;
        if (node >= n) break;
        int g = batch[node];
        if (g != gcur) {
            if (gcur >= 0) {
                atomicAdd(&sums[gcur * DIM + d], acc);
                if (d == 0) atomicAdd(&cnt[gcur], (float)cntv);
            }
            gcur = g;
            acc = 0.f;
            cntv = 0;
        }
        acc += h[(size_t)node * DIM + d];
        cntv++;
    }
    if (gcur >= 0) {
        atomicAdd(&sums[gcur * DIM + d], acc);
        if (d == 0) atomicAdd(&cnt[gcur], (float)cntv);
    }
}

// ---------------- head: mean -> @W2+b2 -> fc1 relu -> fc2 -> out ----------------
__global__ __launch_bounds__(64) void k_head(const float* __restrict__ sums,
                                             const float* __restrict__ cnt,
                                             const float* __restrict__ W2,
                                             const float* __restrict__ b2,
                                             const float* __restrict__ fc1w,
                                             const float* __restrict__ fc1b,
                                             const float* __restrict__ fc2w,
                                             const float* __restrict__ fc2b,
                                             const float* __restrict__ ow,
                                             const float* __restrict__ ob,
                                             float* __restrict__ out) {
    int g = blockIdx.x;
    int t = threadIdx.x;
    __shared__ float gv[64];
    __shared__ float tv[64];
    float c = fmaxf(cnt[g], 1.0f);
    gv[t] = sums[g * DIM + t] / c;
    __syncthreads();
    float acc2 = b2[t];
#pragma unroll
    for (int k = 0; k < 64; ++k) acc2 = fmaf(gv[k], W2[k * 64 + t], acc2);
    tv[t] = acc2;
    __syncthreads();
    float r = 0.0f;
    if (t < 32) {
        float acc = fc1b[t];
#pragma unroll
        for (int k = 0; k < 64; ++k) acc = fmaf(tv[k], fc1w[k * 32 + t], acc);
        acc = fmaxf(acc, 0.0f);
        r = acc * fc2w[t];
    }
#pragma unroll
    for (int off = 16; off; off >>= 1) r += __shfl_down(r, off);
    if (t == 0) out[g] = (r + fc2b[0]) * ow[0] + ob[0];
}

extern "C" void kernel_launch(void* const* d_in, const int* in_sizes, int n_in,
                              void* d_out, int out_size, void* d_ws, size_t ws_size,
                              hipStream_t stream) {
    const float* x   = (const float*)d_in[0];
    const int* eidx  = (const int*)d_in[1];
    const float* ew  = (const float*)d_in[2];
    const int* batch = (const int*)d_in[3];
    const float* W0  = (const float*)d_in[4];
    const float* b0  = (const float*)d_in[5];
    const float* W1  = (const float*)d_in[6];
    const float* b1  = (const float*)d_in[7];
    const float* W2  = (const float*)d_in[8];
    const float* b2  = (const float*)d_in[9];
    const float* fc1w = (const float*)d_in[10];
    const float* fc1b = (const float*)d_in[11];
    const float* fc2w = (const float*)d_in[12];
    const float* fc2b = (const float*)d_in[13];
    const float* ow   = (const float*)d_in[14];
    const float* ob   = (const float*)d_in[15];
    float* out = (float*)d_out;

    const int* row = eidx;
    const int* col = eidx + NE;

    // workspace layout (8B-aligned blocks first)
    char* ws = (char*)d_ws;
    int2* binned           = (int2*)ws;               ws += sizeof(int2) * NE;                 // 12.8MB
    int2* csr              = (int2*)ws;               ws += sizeof(int2) * NE;                 // 12.8MB
    __hip_bfloat16* Xb     = (__hip_bfloat16*)ws;     ws += sizeof(__hip_bfloat16) * (size_t)NN * DIM;
    __hip_bfloat16* Hb     = (__hip_bfloat16*)ws;     ws += sizeof(__hip_bfloat16) * (size_t)NN * DIM;
    float* G               = (float*)ws;              ws += sizeof(float) * (size_t)NN * DIM;  // 25.6MB
    float* dinv            = (float*)ws;              ws += sizeof(float) * NN;
    int*   rowptr          = (int*)ws;                ws += sizeof(int) * (NN + 1);
    int*   gcnt            = (int*)ws;                ws += sizeof(int) * (NBUK + 1);
    int*   boff            = (int*)ws;                ws += sizeof(int) * (NBUK + 1);
    int*   bcur            = (int*)ws;                ws += sizeof(int) * (NBUK + 1);
    float* sums            = (float*)ws;              ws += sizeof(float) * NG * DIM;
    float* cntf            = (float*)ws;              ws += sizeof(float) * NG;

    const int TB = 256;
    int p1_blocks = (NE + EPB - 1) / EPB;  // 391

    // ---- CSR build: block-private bucket reservations (write-merge friendly) ----
    hipMemsetAsync(gcnt, 0, sizeof(int) * NBUK, stream);
    k_ghist<<<p1_blocks, TB, 0, stream>>>(col, gcnt, NE);
    k_gscan<<<1, 256, 0, stream>>>(gcnt, boff, bcur);
    k_part1<<<p1_blocks, TB, 0, stream>>>(row, col, ew, bcur, binned, NE);
    k_p2a<<<NBUK, 256, 0, stream>>>(binned, boff, dinv, rowptr);
    k_p2b<<<NBUK, 256, 0, stream>>>(binned, boff, dinv, rowptr, csr);

    // cast x -> bf16
    int nq = NN * DIM / 4;
    k_cast<<<(nq + TB - 1) / TB, TB, 0, stream>>>(x, (unsigned short*)Xb, nq);

    int gemm_blocks = (NN + 63) / 64;
    int gath_blocks = (NN + 3) / 4;

    // gather-first layers (bf16 pipeline): g = Ahat@X ; X' = relu(g @ W + b)
    k_gather2<false><<<gath_blocks, 256, 0, stream>>>(rowptr, csr, Xb, dinv, Hb, NN);
    k_gemm64v2<<<gemm_blocks, 256, 0, stream>>>((const ushort4*)Hb, W0, b0, (ushort4*)Xb, NN);
    k_gather2<false><<<gath_blocks, 256, 0, stream>>>(rowptr, csr, Xb, dinv, Hb, NN);
    k_gemm64v2<<<gemm_blocks, 256, 0, stream>>>((const ushort4*)Hb, W1, b1, (ushort4*)Xb, NN);
    k_gather2<true><<<gath_blocks, 256, 0, stream>>>(rowptr, csr, Xb, dinv, G, NN);

    // pool over final gather; W2/b2 folded into head
    hipMemsetAsync(sums, 0, sizeof(float) * (NG * DIM + NG), stream);
    k_pool<<<(NN + PCH - 1) / PCH, 256, 0, stream>>>(batch, G, sums, cntf, NN);
    k_head<<<NG, 64, 0, stream>>>(sums, cntf, W2, b2, fc1w, fc1b, fc2w, fc2b, ow, ob, out);
}

// Round 10
// 356.382 us; speedup vs baseline: 2.8347x; 1.0748x over previous
//
#include <hip/hip_runtime.h>
#include <hip/hip_bf16.h>

#define NN 100000
#define NE 1600000
#define DIM 64
#define NG 64

#define NBUK 391      // coarse buckets of 256 nodes: bucket = col >> 8
#define EPB 4096      // edges per pass-1 block

static __device__ __forceinline__ unsigned short bf16bits(float v) {
    __hip_bfloat16 b = __float2bfloat16(v);
    return *reinterpret_cast<unsigned short*>(&b);
}
static __device__ __forceinline__ float bfbits2f(unsigned short u) {
    unsigned int x = ((unsigned int)u) << 16;
    return __uint_as_float(x);
}
// unpack packed bf16x2 dword -> two floats (lo = even dim, hi = odd dim)
static __device__ __forceinline__ void bf2x(unsigned int u, float& lo, float& hi) {
    lo = __uint_as_float(u << 16);
    hi = __uint_as_float(u & 0xFFFF0000u);
}

// ---------------- global bucket histogram (LDS-aggregated) ----------------
__global__ __launch_bounds__(256) void k_ghist(const int* __restrict__ col,
                                               int* gcnt, int E) {
    __shared__ int hist[NBUK];
    int t = threadIdx.x;
    for (int i = t; i < NBUK; i += 256) hist[i] = 0;
    __syncthreads();
    int e0 = blockIdx.x * EPB, e1 = min(e0 + EPB, E);
    for (int e = e0 + t; e < e1; e += 256) atomicAdd(&hist[col[e] >> 8], 1);
    __syncthreads();
    for (int i = t; i < NBUK; i += 256)
        if (hist[i]) atomicAdd(&gcnt[i], hist[i]);
}

// ---------------- bucket offsets scan (one block) + zero pool buffers ----------
__global__ __launch_bounds__(256) void k_gscan(const int* __restrict__ gcnt,
                                               int* __restrict__ boff,
                                               int* __restrict__ bcur,
                                               float* __restrict__ sums,
                                               float* __restrict__ cntf) {
    __shared__ int sm[256];
    int t = threadIdx.x;
    // fold in pool-accumulator zeroing (saves a memset dispatch)
    for (int i = t; i < NG * DIM; i += 256) sums[i] = 0.f;
    if (t < NG) cntf[t] = 0.f;
    int v0 = (2 * t < NBUK) ? gcnt[2 * t] : 0;
    int v1 = (2 * t + 1 < NBUK) ? gcnt[2 * t + 1] : 0;
    int s = v0 + v1;
    sm[t] = s;
    __syncthreads();
    for (int off = 1; off < 256; off <<= 1) {
        int tmp = (t >= off) ? sm[t - off] : 0;
        __syncthreads();
        sm[t] += tmp;
        __syncthreads();
    }
    int run = sm[t] - s;
    if (2 * t < NBUK) { boff[2 * t] = run; bcur[2 * t] = run; }
    run += v0;
    if (2 * t + 1 < NBUK) { boff[2 * t + 1] = run; bcur[2 * t + 1] = run; }
    if (t == 255) boff[NBUK] = run + v1;  // == NE
}

// ---------------- pass 1: block-local counting sort into bucket ranges ----------
// binned record: .x = (cl<<17)|row  (cl = col&255, row<2^17), .y = ew bits
__global__ __launch_bounds__(256) void k_part1(const int* __restrict__ row,
                                               const int* __restrict__ col,
                                               const float* __restrict__ ew,
                                               int* bcur, int2* __restrict__ binned,
                                               int E) {
    __shared__ int hist[NBUK];
    __shared__ int base_s[NBUK];
    int t = threadIdx.x;
    for (int i = t; i < NBUK; i += 256) hist[i] = 0;
    __syncthreads();
    int e0 = blockIdx.x * EPB, e1 = min(e0 + EPB, E);
    for (int e = e0 + t; e < e1; e += 256) atomicAdd(&hist[col[e] >> 8], 1);
    __syncthreads();
    for (int i = t; i < NBUK; i += 256) {
        int c = hist[i];
        base_s[i] = c ? atomicAdd(&bcur[i], c) : 0;
        hist[i] = 0;  // reuse as local cursor
    }
    __syncthreads();
    for (int e = e0 + t; e < e1; e += 256) {
        int c = col[e];
        int b = c >> 8, cl = c & 255;
        int rk = atomicAdd(&hist[b], 1);
        binned[base_s[b] + rk] = make_int2((cl << 17) | row[e], __float_as_int(ew[e]));
    }
}

// ---------------- pass 2a: per-bucket degree (fixed-point) + rowptr + dinv --------
__global__ __launch_bounds__(256) void k_p2a(const int2* __restrict__ binned,
                                             const int* __restrict__ boff,
                                             float* __restrict__ dinv,
                                             int* __restrict__ rowptr) {
    int b = blockIdx.x, t = threadIdx.x;
    __shared__ unsigned int dsum[256];
    __shared__ int ncnt[256];
    __shared__ int sm[256];
    dsum[t] = 0;
    ncnt[t] = 0;
    __syncthreads();
    int e0 = boff[b], e1 = boff[b + 1];
    for (int e = e0 + t; e < e1; e += 256) {
        int2 v = binned[e];
        int cl = v.x >> 17;
        atomicAdd(&ncnt[cl], 1);
        unsigned int fx = (unsigned int)__float2uint_rn(__int_as_float(v.y) * 16777216.0f);
        atomicAdd(&dsum[cl], fx);
    }
    __syncthreads();
    int c = ncnt[t];
    sm[t] = c;
    __syncthreads();
    for (int off = 1; off < 256; off <<= 1) {
        int tmp = (t >= off) ? sm[t - off] : 0;
        __syncthreads();
        sm[t] += tmp;
        __syncthreads();
    }
    int node = b * 256 + t;
    if (node < NN) {
        rowptr[node] = e0 + sm[t] - c;
        dinv[node] = rsqrtf(1.0f + (float)dsum[t] * (1.0f / 16777216.0f));
    }
    if (b == 0 && t == 0) rowptr[NN] = NE;
}

// ---------------- pass 2b: per-bucket CSR place (contiguous window) ----------------
__global__ __launch_bounds__(256) void k_p2b(const int2* __restrict__ binned,
                                             const int* __restrict__ boff,
                                             const float* __restrict__ dinv,
                                             const int* __restrict__ rowptr,
                                             int2* __restrict__ csr) {
    int b = blockIdx.x, t = threadIdx.x;
    __shared__ int ncur[256];
    __shared__ float ldin[256];
    int node = b * 256 + t;
    ncur[t] = (node < NN) ? rowptr[node] : 0;
    ldin[t] = (node < NN) ? dinv[node] : 0.f;
    __syncthreads();
    int e0 = boff[b], e1 = boff[b + 1];
    for (int e = e0 + t; e < e1; e += 256) {
        int2 v = binned[e];
        int cl = v.x >> 17, r = v.x & 0x1FFFF;
        float nm = dinv[r] * __int_as_float(v.y) * ldin[cl];
        int p = atomicAdd(&ncur[cl], 1);
        csr[p] = make_int2(r, __float_as_int(nm));
    }
}

// ---------------- cast x -> bf16 ----------------
__global__ void k_cast(const float* __restrict__ x, unsigned short* __restrict__ xb, int nq) {
    int i = blockIdx.x * blockDim.x + threadIdx.x;
    if (i >= nq) return;
    float4 v = ((const float4*)x)[i];
    ushort4 o;
    o.x = bf16bits(v.x);
    o.y = bf16bits(v.y);
    o.z = bf16bits(v.z);
    o.w = bf16bits(v.w);
    ((ushort4*)xb)[i] = o;
}

// ---------------- gather v3: 8 lanes x 16B per row, 8 edges per wave-instr -------
// lane = (g = l>>3, sub = l&7); group g walks edges e0+g, e0+g+8, ...
// each lane covers dims [sub*8, sub*8+8) as one uint4 (8 bf16); 3-level shfl merge.
template <bool F32OUT>
__global__ __launch_bounds__(256) void k_gather3(const int* __restrict__ rowptr,
                                                 const int2* __restrict__ csr,
                                                 const uint4* __restrict__ h8,
                                                 const float* __restrict__ dinv,
                                                 void* __restrict__ out, int n) {
    int node = blockIdx.x * 4 + (threadIdx.x >> 6);
    if (node >= n) return;
    int l = threadIdx.x & 63;
    int g = l >> 3, sub = l & 7;
    float acc[8];
#pragma unroll
    for (int i = 0; i < 8; ++i) acc[i] = 0.f;
    if (g == 0) {  // self-loop term
        float di = dinv[node];
        float s = di * di;
        uint4 v = h8[(size_t)node * 8 + sub];
        float lo, hi;
        bf2x(v.x, lo, hi); acc[0] = lo * s; acc[1] = hi * s;
        bf2x(v.y, lo, hi); acc[2] = lo * s; acc[3] = hi * s;
        bf2x(v.z, lo, hi); acc[4] = lo * s; acc[5] = hi * s;
        bf2x(v.w, lo, hi); acc[6] = lo * s; acc[7] = hi * s;
    }
    int e = rowptr[node] + g, e1 = rowptr[node + 1];
    for (; e + 8 < e1; e += 16) {  // unroll 2: two rows in flight per group
        int2 p0 = csr[e];
        int2 p1 = csr[e + 8];
        uint4 r0 = h8[(size_t)p0.x * 8 + sub];
        uint4 r1 = h8[(size_t)p1.x * 8 + sub];
        float n0 = __int_as_float(p0.y), n1 = __int_as_float(p1.y);
        float lo, hi;
        bf2x(r0.x, lo, hi); acc[0] = fmaf(lo, n0, acc[0]); acc[1] = fmaf(hi, n0, acc[1]);
        bf2x(r0.y, lo, hi); acc[2] = fmaf(lo, n0, acc[2]); acc[3] = fmaf(hi, n0, acc[3]);
        bf2x(r0.z, lo, hi); acc[4] = fmaf(lo, n0, acc[4]); acc[5] = fmaf(hi, n0, acc[5]);
        bf2x(r0.w, lo, hi); acc[6] = fmaf(lo, n0, acc[6]); acc[7] = fmaf(hi, n0, acc[7]);
        bf2x(r1.x, lo, hi); acc[0] = fmaf(lo, n1, acc[0]); acc[1] = fmaf(hi, n1, acc[1]);
        bf2x(r1.y, lo, hi); acc[2] = fmaf(lo, n1, acc[2]); acc[3] = fmaf(hi, n1, acc[3]);
        bf2x(r1.z, lo, hi); acc[4] = fmaf(lo, n1, acc[4]); acc[5] = fmaf(hi, n1, acc[5]);
        bf2x(r1.w, lo, hi); acc[6] = fmaf(lo, n1, acc[6]); acc[7] = fmaf(hi, n1, acc[7]);
    }
    if (e < e1) {
        int2 p = csr[e];
        uint4 r = h8[(size_t)p.x * 8 + sub];
        float nm = __int_as_float(p.y);
        float lo, hi;
        bf2x(r.x, lo, hi); acc[0] = fmaf(lo, nm, acc[0]); acc[1] = fmaf(hi, nm, acc[1]);
        bf2x(r.y, lo, hi); acc[2] = fmaf(lo, nm, acc[2]); acc[3] = fmaf(hi, nm, acc[3]);
        bf2x(r.z, lo, hi); acc[4] = fmaf(lo, nm, acc[4]); acc[5] = fmaf(hi, nm, acc[5]);
        bf2x(r.w, lo, hi); acc[6] = fmaf(lo, nm, acc[6]); acc[7] = fmaf(hi, nm, acc[7]);
    }
    // merge the 8 groups (lanes converged here)
#pragma unroll
    for (int off = 8; off <= 32; off <<= 1) {
#pragma unroll
        for (int i = 0; i < 8; ++i) acc[i] += __shfl_xor(acc[i], off);
    }
    if (g == 0) {
        if (F32OUT) {
            float4 f0 = make_float4(acc[0], acc[1], acc[2], acc[3]);
            float4 f1 = make_float4(acc[4], acc[5], acc[6], acc[7]);
            ((float4*)out)[(size_t)node * 16 + sub * 2 + 0] = f0;
            ((float4*)out)[(size_t)node * 16 + sub * 2 + 1] = f1;
        } else {
            uint4 o;
            o.x = ((unsigned int)bf16bits(acc[1]) << 16) | bf16bits(acc[0]);
            o.y = ((unsigned int)bf16bits(acc[3]) << 16) | bf16bits(acc[2]);
            o.z = ((unsigned int)bf16bits(acc[5]) << 16) | bf16bits(acc[4]);
            o.w = ((unsigned int)bf16bits(acc[7]) << 16) | bf16bits(acc[6]);
            ((uint4*)out)[(size_t)node * 8 + sub] = o;
        }
    }
}

// ---------------- GEMM v2: 64-node tile, 4x4 register tile, float4 LDS reads ------
__global__ __launch_bounds__(256) void k_gemm64v2(const ushort4* __restrict__ in,
                                                  const float* __restrict__ W,
                                                  const float* __restrict__ b,
                                                  ushort4* __restrict__ out, int n) {
    __shared__ float sW[64][64];   // [k][d]
    __shared__ float sX[64][68];   // [node][k], +4 pad
    int tid = threadIdx.x;
#pragma unroll
    for (int i = 0; i < 4; ++i) {
        int q = tid + i * 256;
        ((float4*)&sW[0][0])[q] = ((const float4*)W)[q];
    }
    int base = blockIdx.x * 64;
#pragma unroll
    for (int i = 0; i < 4; ++i) {
        int idx = tid + i * 256;  // 0..1023
        int r = idx >> 4, q = idx & 15;
        int node = base + r;
        float4 f = make_float4(0.f, 0.f, 0.f, 0.f);
        if (node < n) {
            ushort4 v = in[(size_t)node * 16 + q];
            f.x = bfbits2f(v.x);
            f.y = bfbits2f(v.y);
            f.z = bfbits2f(v.z);
            f.w = bfbits2f(v.w);
        }
        *(float4*)&sX[r][q * 4] = f;
    }
    __syncthreads();
    int ng = tid >> 4;
    int dg = tid & 15;
    float acc[4][4];
#pragma unroll
    for (int i = 0; i < 4; ++i)
#pragma unroll
        for (int j = 0; j < 4; ++j) acc[i][j] = 0.f;
#pragma unroll
    for (int k4 = 0; k4 < 16; ++k4) {
        float4 xr[4];
#pragma unroll
        for (int i = 0; i < 4; ++i) xr[i] = *(const float4*)&sX[ng * 4 + i][k4 * 4];
        float4 wc[4];
#pragma unroll
        for (int j = 0; j < 4; ++j) wc[j] = *(const float4*)&sW[k4 * 4 + j][dg * 4];
#pragma unroll
        for (int i = 0; i < 4; ++i) {
            acc[i][0] = fmaf(xr[i].x, wc[0].x, acc[i][0]);
            acc[i][1] = fmaf(xr[i].x, wc[0].y, acc[i][1]);
            acc[i][2] = fmaf(xr[i].x, wc[0].z, acc[i][2]);
            acc[i][3] = fmaf(xr[i].x, wc[0].w, acc[i][3]);
            acc[i][0] = fmaf(xr[i].y, wc[1].x, acc[i][0]);
            acc[i][1] = fmaf(xr[i].y, wc[1].y, acc[i][1]);
            acc[i][2] = fmaf(xr[i].y, wc[1].z, acc[i][2]);
            acc[i][3] = fmaf(xr[i].y, wc[1].w, acc[i][3]);
            acc[i][0] = fmaf(xr[i].z, wc[2].x, acc[i][0]);
            acc[i][1] = fmaf(xr[i].z, wc[2].y, acc[i][1]);
            acc[i][2] = fmaf(xr[i].z, wc[2].z, acc[i][2]);
            acc[i][3] = fmaf(xr[i].z, wc[2].w, acc[i][3]);
            acc[i][0] = fmaf(xr[i].w, wc[3].x, acc[i][0]);
            acc[i][1] = fmaf(xr[i].w, wc[3].y, acc[i][1]);
            acc[i][2] = fmaf(xr[i].w, wc[3].z, acc[i][2]);
            acc[i][3] = fmaf(xr[i].w, wc[3].w, acc[i][3]);
        }
    }
    float4 bv = ((const float4*)b)[dg];
#pragma unroll
    for (int i = 0; i < 4; ++i) {
        int node = base + ng * 4 + i;
        if (node < n) {
            ushort4 o;
            o.x = bf16bits(fmaxf(acc[i][0] + bv.x, 0.f));
            o.y = bf16bits(fmaxf(acc[i][1] + bv.y, 0.f));
            o.z = bf16bits(fmaxf(acc[i][2] + bv.z, 0.f));
            o.w = bf16bits(fmaxf(acc[i][3] + bv.w, 0.f));
            out[(size_t)node * 16 + dg] = o;
        }
    }
}

// ---------------- pooling (batch sorted -> run-length partial sums) ----------
#define PCH 256
__global__ __launch_bounds__(256) void k_pool(const int* __restrict__ batch,
                                              const float* __restrict__ h,
                                              float* sums, float* cnt, int n) {
    int t = threadIdx.x;
    int d = t & 63, s = t >> 6;
    int base = blockIdx.x * PCH;
    float acc = 0.f;
    int gcur = -1, cntv = 0;
    for (int i = s; i < PCH; i += 4) {
        int node = base + i;
        if (node >= n) break;
        int g = batch[node];
        if (g != gcur) {
            if (gcur >= 0) {
                atomicAdd(&sums[gcur * DIM + d], acc);
                if (d == 0) atomicAdd(&cnt[gcur], (float)cntv);
            }
            gcur = g;
            acc = 0.f;
            cntv = 0;
        }
        acc += h[(size_t)node * DIM + d];
        cntv++;
    }
    if (gcur >= 0) {
        atomicAdd(&sums[gcur * DIM + d], acc);
        if (d == 0) atomicAdd(&cnt[gcur], (float)cntv);
    }
}

// ---------------- head: mean -> @W2+b2 -> fc1 relu -> fc2 -> out ----------------
__global__ __launch_bounds__(64) void k_head(const float* __restrict__ sums,
                                             const float* __restrict__ cnt,
                                             const float* __restrict__ W2,
                                             const float* __restrict__ b2,
                                             const float* __restrict__ fc1w,
                                             const float* __restrict__ fc1b,
                                             const float* __restrict__ fc2w,
                                             const float* __restrict__ fc2b,
                                             const float* __restrict__ ow,
                                             const float* __restrict__ ob,
                                             float* __restrict__ out) {
    int g = blockIdx.x;
    int t = threadIdx.x;
    __shared__ float gv[64];
    __shared__ float tv[64];
    float c = fmaxf(cnt[g], 1.0f);
    gv[t] = sums[g * DIM + t] / c;
    __syncthreads();
    float acc2 = b2[t];
#pragma unroll
    for (int k = 0; k < 64; ++k) acc2 = fmaf(gv[k], W2[k * 64 + t], acc2);
    tv[t] = acc2;
    __syncthreads();
    float r = 0.0f;
    if (t < 32) {
        float acc = fc1b[t];
#pragma unroll
        for (int k = 0; k < 64; ++k) acc = fmaf(tv[k], fc1w[k * 32 + t], acc);
        acc = fmaxf(acc, 0.0f);
        r = acc * fc2w[t];
    }
#pragma unroll
    for (int off = 16; off; off >>= 1) r += __shfl_down(r, off);
    if (t == 0) out[g] = (r + fc2b[0]) * ow[0] + ob[0];
}

extern "C" void kernel_launch(void* const* d_in, const int* in_sizes, int n_in,
                              void* d_out, int out_size, void* d_ws, size_t ws_size,
                              hipStream_t stream) {
    const float* x   = (const float*)d_in[0];
    const int* eidx  = (const int*)d_in[1];
    const float* ew  = (const float*)d_in[2];
    const int* batch = (const int*)d_in[3];
    const float* W0  = (const float*)d_in[4];
    const float* b0  = (const float*)d_in[5];
    const float* W1  = (const float*)d_in[6];
    const float* b1  = (const float*)d_in[7];
    const float* W2  = (const float*)d_in[8];
    const float* b2  = (const float*)d_in[9];
    const float* fc1w = (const float*)d_in[10];
    const float* fc1b = (const float*)d_in[11];
    const float* fc2w = (const float*)d_in[12];
    const float* fc2b = (const float*)d_in[13];
    const float* ow   = (const float*)d_in[14];
    const float* ob   = (const float*)d_in[15];
    float* out = (float*)d_out;

    const int* row = eidx;
    const int* col = eidx + NE;

    // workspace layout (16B-aligned blocks first)
    char* ws = (char*)d_ws;
    int2* binned           = (int2*)ws;               ws += sizeof(int2) * NE;                 // 12.8MB
    int2* csr              = (int2*)ws;               ws += sizeof(int2) * NE;                 // 12.8MB
    __hip_bfloat16* Xb     = (__hip_bfloat16*)ws;     ws += sizeof(__hip_bfloat16) * (size_t)NN * DIM;
    __hip_bfloat16* Hb     = (__hip_bfloat16*)ws;     ws += sizeof(__hip_bfloat16) * (size_t)NN * DIM;
    float* G               = (float*)ws;              ws += sizeof(float) * (size_t)NN * DIM;  // 25.6MB
    float* dinv            = (float*)ws;              ws += sizeof(float) * NN;
    int*   rowptr          = (int*)ws;                ws += sizeof(int) * (NN + 1);
    int*   gcnt            = (int*)ws;                ws += sizeof(int) * (NBUK + 1);
    int*   boff            = (int*)ws;                ws += sizeof(int) * (NBUK + 1);
    int*   bcur            = (int*)ws;                ws += sizeof(int) * (NBUK + 1);
    float* sums            = (float*)ws;              ws += sizeof(float) * NG * DIM;
    float* cntf            = (float*)ws;              ws += sizeof(float) * NG;

    const int TB = 256;
    int p1_blocks = (NE + EPB - 1) / EPB;  // 391

    // ---- CSR build: block-private bucket reservations (write-merge friendly) ----
    hipMemsetAsync(gcnt, 0, sizeof(int) * NBUK, stream);
    k_ghist<<<p1_blocks, TB, 0, stream>>>(col, gcnt, NE);
    k_gscan<<<1, 256, 0, stream>>>(gcnt, boff, bcur, sums, cntf);
    k_part1<<<p1_blocks, TB, 0, stream>>>(row, col, ew, bcur, binned, NE);
    k_p2a<<<NBUK, 256, 0, stream>>>(binned, boff, dinv, rowptr);
    k_p2b<<<NBUK, 256, 0, stream>>>(binned, boff, dinv, rowptr, csr);

    // cast x -> bf16
    int nq = NN * DIM / 4;
    k_cast<<<(nq + TB - 1) / TB, TB, 0, stream>>>(x, (unsigned short*)Xb, nq);

    int gemm_blocks = (NN + 63) / 64;
    int gath_blocks = (NN + 3) / 4;

    // gather-first layers (bf16 pipeline): g = Ahat@X ; X' = relu(g @ W + b)
    k_gather3<false><<<gath_blocks, 256, 0, stream>>>(rowptr, csr, (const uint4*)Xb, dinv, Hb, NN);
    k_gemm64v2<<<gemm_blocks, 256, 0, stream>>>((const ushort4*)Hb, W0, b0, (ushort4*)Xb, NN);
    k_gather3<false><<<gath_blocks, 256, 0, stream>>>(rowptr, csr, (const uint4*)Xb, dinv, Hb, NN);
    k_gemm64v2<<<gemm_blocks, 256, 0, stream>>>((const ushort4*)Hb, W1, b1, (ushort4*)Xb, NN);
    k_gather3<true><<<gath_blocks, 256, 0, stream>>>(rowptr, csr, (const uint4*)Xb, dinv, G, NN);

    // pool over final gather; W2/b2 folded into head
    k_pool<<<(NN + PCH - 1) / PCH, 256, 0, stream>>>(batch, G, sums, cntf, NN);
    k_head<<<NG, 64, 0, stream>>>(sums, cntf, W2, b2, fc1w, fc1b, fc2w, fc2b, ow, ob, out);
}

// Round 11
// 294.276 us; speedup vs baseline: 3.4329x; 1.2110x over previous
//
#include <hip/hip_runtime.h>
#include <hip/hip_bf16.h>

#define NN 100000
#define NE 1600000
#define DIM 64
#define NG 64

#define NBUK 391      // coarse buckets of 256 nodes: bucket = col >> 8
#define EPB 4096      // edges per pass-1 block

static __device__ __forceinline__ unsigned short bf16bits(float v) {
    __hip_bfloat16 b = __float2bfloat16(v);
    return *reinterpret_cast<unsigned short*>(&b);
}
static __device__ __forceinline__ float bfbits2f(unsigned short u) {
    unsigned int x = ((unsigned int)u) << 16;
    return __uint_as_float(x);
}
// unpack packed bf16x2 dword -> two floats (lo = even dim, hi = odd dim)
static __device__ __forceinline__ void bf2x(unsigned int u, float& lo, float& hi) {
    lo = __uint_as_float(u << 16);
    hi = __uint_as_float(u & 0xFFFF0000u);
}

// ---------------- global bucket histogram (LDS-aggregated) ----------------
__global__ __launch_bounds__(256) void k_ghist(const int* __restrict__ col,
                                               int* gcnt, int E) {
    __shared__ int hist[NBUK];
    int t = threadIdx.x;
    for (int i = t; i < NBUK; i += 256) hist[i] = 0;
    __syncthreads();
    int e0 = blockIdx.x * EPB, e1 = min(e0 + EPB, E);
    for (int e = e0 + t; e < e1; e += 256) atomicAdd(&hist[col[e] >> 8], 1);
    __syncthreads();
    for (int i = t; i < NBUK; i += 256)
        if (hist[i]) atomicAdd(&gcnt[i], hist[i]);
}

// ---------------- bucket offsets scan (one block) + zero pool buffers ----------
__global__ __launch_bounds__(256) void k_gscan(const int* __restrict__ gcnt,
                                               int* __restrict__ boff,
                                               int* __restrict__ bcur,
                                               float* __restrict__ sums,
                                               float* __restrict__ cntf) {
    __shared__ int sm[256];
    int t = threadIdx.x;
    for (int i = t; i < NG * DIM; i += 256) sums[i] = 0.f;
    if (t < NG) cntf[t] = 0.f;
    int v0 = (2 * t < NBUK) ? gcnt[2 * t] : 0;
    int v1 = (2 * t + 1 < NBUK) ? gcnt[2 * t + 1] : 0;
    int s = v0 + v1;
    sm[t] = s;
    __syncthreads();
    for (int off = 1; off < 256; off <<= 1) {
        int tmp = (t >= off) ? sm[t - off] : 0;
        __syncthreads();
        sm[t] += tmp;
        __syncthreads();
    }
    int run = sm[t] - s;
    if (2 * t < NBUK) { boff[2 * t] = run; bcur[2 * t] = run; }
    run += v0;
    if (2 * t + 1 < NBUK) { boff[2 * t + 1] = run; bcur[2 * t + 1] = run; }
    if (t == 255) boff[NBUK] = run + v1;  // == NE
}

// ---------------- pass 1: block-local counting sort into bucket ranges ----------
// binned record: .x = (cl<<17)|row  (cl = col&255, row<2^17), .y = ew bits
__global__ __launch_bounds__(256) void k_part1(const int* __restrict__ row,
                                               const int* __restrict__ col,
                                               const float* __restrict__ ew,
                                               int* bcur, int2* __restrict__ binned,
                                               int E) {
    __shared__ int hist[NBUK];
    __shared__ int base_s[NBUK];
    int t = threadIdx.x;
    for (int i = t; i < NBUK; i += 256) hist[i] = 0;
    __syncthreads();
    int e0 = blockIdx.x * EPB, e1 = min(e0 + EPB, E);
    for (int e = e0 + t; e < e1; e += 256) atomicAdd(&hist[col[e] >> 8], 1);
    __syncthreads();
    for (int i = t; i < NBUK; i += 256) {
        int c = hist[i];
        base_s[i] = c ? atomicAdd(&bcur[i], c) : 0;
        hist[i] = 0;  // reuse as local cursor
    }
    __syncthreads();
    for (int e = e0 + t; e < e1; e += 256) {
        int c = col[e];
        int b = c >> 8, cl = c & 255;
        int rk = atomicAdd(&hist[b], 1);
        binned[base_s[b] + rk] = make_int2((cl << 17) | row[e], __float_as_int(ew[e]));
    }
}

// ---------------- pass 2a: per-bucket degree (fixed-point) + rowptr + dinv --------
__global__ __launch_bounds__(256) void k_p2a(const int2* __restrict__ binned,
                                             const int* __restrict__ boff,
                                             float* __restrict__ dinv,
                                             int* __restrict__ rowptr) {
    int b = blockIdx.x, t = threadIdx.x;
    __shared__ unsigned int dsum[256];
    __shared__ int ncnt[256];
    __shared__ int sm[256];
    dsum[t] = 0;
    ncnt[t] = 0;
    __syncthreads();
    int e0 = boff[b], e1 = boff[b + 1];
    for (int e = e0 + t; e < e1; e += 256) {
        int2 v = binned[e];
        int cl = v.x >> 17;
        atomicAdd(&ncnt[cl], 1);
        unsigned int fx = (unsigned int)__float2uint_rn(__int_as_float(v.y) * 16777216.0f);
        atomicAdd(&dsum[cl], fx);
    }
    __syncthreads();
    int c = ncnt[t];
    sm[t] = c;
    __syncthreads();
    for (int off = 1; off < 256; off <<= 1) {
        int tmp = (t >= off) ? sm[t - off] : 0;
        __syncthreads();
        sm[t] += tmp;
        __syncthreads();
    }
    int node = b * 256 + t;
    if (node < NN) {
        rowptr[node] = e0 + sm[t] - c;
        dinv[node] = rsqrtf(1.0f + (float)dsum[t] * (1.0f / 16777216.0f));
    }
    if (b == 0 && t == 0) rowptr[NN] = NE;
}

// ---------------- pass 2b: per-bucket CSR place (contiguous window) ----------------
__global__ __launch_bounds__(256) void k_p2b(const int2* __restrict__ binned,
                                             const int* __restrict__ boff,
                                             const float* __restrict__ dinv,
                                             const int* __restrict__ rowptr,
                                             int2* __restrict__ csr) {
    int b = blockIdx.x, t = threadIdx.x;
    __shared__ int ncur[256];
    __shared__ float ldin[256];
    int node = b * 256 + t;
    ncur[t] = (node < NN) ? rowptr[node] : 0;
    ldin[t] = (node < NN) ? dinv[node] : 0.f;
    __syncthreads();
    int e0 = boff[b], e1 = boff[b + 1];
    for (int e = e0 + t; e < e1; e += 256) {
        int2 v = binned[e];
        int cl = v.x >> 17, r = v.x & 0x1FFFF;
        float nm = dinv[r] * __int_as_float(v.y) * ldin[cl];
        int p = atomicAdd(&ncur[cl], 1);
        csr[p] = make_int2(r, __float_as_int(nm));
    }
}

// ---------------- cast x -> bf16 ----------------
__global__ void k_cast(const float* __restrict__ x, unsigned short* __restrict__ xb, int nq) {
    int i = blockIdx.x * blockDim.x + threadIdx.x;
    if (i >= nq) return;
    float4 v = ((const float4*)x)[i];
    ushort4 o;
    o.x = bf16bits(v.x);
    o.y = bf16bits(v.y);
    o.z = bf16bits(v.z);
    o.w = bf16bits(v.w);
    ((ushort4*)xb)[i] = o;
}

// ---------------- gather v3: 8 lanes x 16B per row, 8 edges per wave-instr -------
template <bool F32OUT>
__global__ __launch_bounds__(256) void k_gather3(const int* __restrict__ rowptr,
                                                 const int2* __restrict__ csr,
                                                 const uint4* __restrict__ h8,
                                                 const float* __restrict__ dinv,
                                                 void* __restrict__ out, int n) {
    int node = blockIdx.x * 4 + (threadIdx.x >> 6);
    if (node >= n) return;
    int l = threadIdx.x & 63;
    int g = l >> 3, sub = l & 7;
    float acc[8];
#pragma unroll
    for (int i = 0; i < 8; ++i) acc[i] = 0.f;
    if (g == 0) {  // self-loop term
        float di = dinv[node];
        float s = di * di;
        uint4 v = h8[(size_t)node * 8 + sub];
        float lo, hi;
        bf2x(v.x, lo, hi); acc[0] = lo * s; acc[1] = hi * s;
        bf2x(v.y, lo, hi); acc[2] = lo * s; acc[3] = hi * s;
        bf2x(v.z, lo, hi); acc[4] = lo * s; acc[5] = hi * s;
        bf2x(v.w, lo, hi); acc[6] = lo * s; acc[7] = hi * s;
    }
    int e = rowptr[node] + g, e1 = rowptr[node + 1];
    for (; e + 8 < e1; e += 16) {  // unroll 2: two rows in flight per group
        int2 p0 = csr[e];
        int2 p1 = csr[e + 8];
        uint4 r0 = h8[(size_t)p0.x * 8 + sub];
        uint4 r1 = h8[(size_t)p1.x * 8 + sub];
        float n0 = __int_as_float(p0.y), n1 = __int_as_float(p1.y);
        float lo, hi;
        bf2x(r0.x, lo, hi); acc[0] = fmaf(lo, n0, acc[0]); acc[1] = fmaf(hi, n0, acc[1]);
        bf2x(r0.y, lo, hi); acc[2] = fmaf(lo, n0, acc[2]); acc[3] = fmaf(hi, n0, acc[3]);
        bf2x(r0.z, lo, hi); acc[4] = fmaf(lo, n0, acc[4]); acc[5] = fmaf(hi, n0, acc[5]);
        bf2x(r0.w, lo, hi); acc[6] = fmaf(lo, n0, acc[6]); acc[7] = fmaf(hi, n0, acc[7]);
        bf2x(r1.x, lo, hi); acc[0] = fmaf(lo, n1, acc[0]); acc[1] = fmaf(hi, n1, acc[1]);
        bf2x(r1.y, lo, hi); acc[2] = fmaf(lo, n1, acc[2]); acc[3] = fmaf(hi, n1, acc[3]);
        bf2x(r1.z, lo, hi); acc[4] = fmaf(lo, n1, acc[4]); acc[5] = fmaf(hi, n1, acc[5]);
        bf2x(r1.w, lo, hi); acc[6] = fmaf(lo, n1, acc[6]); acc[7] = fmaf(hi, n1, acc[7]);
    }
    if (e < e1) {
        int2 p = csr[e];
        uint4 r = h8[(size_t)p.x * 8 + sub];
        float nm = __int_as_float(p.y);
        float lo, hi;
        bf2x(r.x, lo, hi); acc[0] = fmaf(lo, nm, acc[0]); acc[1] = fmaf(hi, nm, acc[1]);
        bf2x(r.y, lo, hi); acc[2] = fmaf(lo, nm, acc[2]); acc[3] = fmaf(hi, nm, acc[3]);
        bf2x(r.z, lo, hi); acc[4] = fmaf(lo, nm, acc[4]); acc[5] = fmaf(hi, nm, acc[5]);
        bf2x(r.w, lo, hi); acc[6] = fmaf(lo, nm, acc[6]); acc[7] = fmaf(hi, nm, acc[7]);
    }
#pragma unroll
    for (int off = 8; off <= 32; off <<= 1) {
#pragma unroll
        for (int i = 0; i < 8; ++i) acc[i] += __shfl_xor(acc[i], off);
    }
    if (g == 0) {
        if (F32OUT) {
            float4 f0 = make_float4(acc[0], acc[1], acc[2], acc[3]);
            float4 f1 = make_float4(acc[4], acc[5], acc[6], acc[7]);
            ((float4*)out)[(size_t)node * 16 + sub * 2 + 0] = f0;
            ((float4*)out)[(size_t)node * 16 + sub * 2 + 1] = f1;
        } else {
            uint4 o;
            o.x = ((unsigned int)bf16bits(acc[1]) << 16) | bf16bits(acc[0]);
            o.y = ((unsigned int)bf16bits(acc[3]) << 16) | bf16bits(acc[2]);
            o.z = ((unsigned int)bf16bits(acc[5]) << 16) | bf16bits(acc[4]);
            o.w = ((unsigned int)bf16bits(acc[7]) << 16) | bf16bits(acc[6]);
            ((uint4*)out)[(size_t)node * 8 + sub] = o;
        }
    }
}

// ---------------- GEMM v3: 64-node tile, 4x4 register tile, register-capped ------
// __launch_bounds__(256,4): VGPR cap 128 -> 4 blocks/CU (LDS-limited), 16 waves/CU.
// #pragma unroll 4 keeps the live set ~80 VGPR (full unroll ballooned to 256).
__global__ __launch_bounds__(256, 4) void k_gemm64v3(const ushort4* __restrict__ in,
                                                     const float* __restrict__ W,
                                                     const float* __restrict__ b,
                                                     ushort4* __restrict__ out, int n) {
    __shared__ float sW[64][64];   // [k][d]
    __shared__ float sX[64][68];   // [node][k], +4 pad
    int tid = threadIdx.x;
#pragma unroll
    for (int i = 0; i < 4; ++i) {
        int q = tid + i * 256;
        ((float4*)&sW[0][0])[q] = ((const float4*)W)[q];
    }
    int base = blockIdx.x * 64;
#pragma unroll
    for (int i = 0; i < 4; ++i) {
        int idx = tid + i * 256;  // 0..1023
        int r = idx >> 4, q = idx & 15;
        int node = base + r;
        float4 f = make_float4(0.f, 0.f, 0.f, 0.f);
        if (node < n) {
            ushort4 v = in[(size_t)node * 16 + q];
            f.x = bfbits2f(v.x);
            f.y = bfbits2f(v.y);
            f.z = bfbits2f(v.z);
            f.w = bfbits2f(v.w);
        }
        *(float4*)&sX[r][q * 4] = f;
    }
    __syncthreads();
    int ng = tid >> 4;
    int dg = tid & 15;
    float acc[4][4];
#pragma unroll
    for (int i = 0; i < 4; ++i)
#pragma unroll
        for (int j = 0; j < 4; ++j) acc[i][j] = 0.f;
#pragma unroll 4
    for (int k4 = 0; k4 < 16; ++k4) {
        float4 xr[4];
#pragma unroll
        for (int i = 0; i < 4; ++i) xr[i] = *(const float4*)&sX[ng * 4 + i][k4 * 4];
        float4 wc[4];
#pragma unroll
        for (int j = 0; j < 4; ++j) wc[j] = *(const float4*)&sW[k4 * 4 + j][dg * 4];
#pragma unroll
        for (int i = 0; i < 4; ++i) {
            acc[i][0] = fmaf(xr[i].x, wc[0].x, acc[i][0]);
            acc[i][1] = fmaf(xr[i].x, wc[0].y, acc[i][1]);
            acc[i][2] = fmaf(xr[i].x, wc[0].z, acc[i][2]);
            acc[i][3] = fmaf(xr[i].x, wc[0].w, acc[i][3]);
            acc[i][0] = fmaf(xr[i].y, wc[1].x, acc[i][0]);
            acc[i][1] = fmaf(xr[i].y, wc[1].y, acc[i][1]);
            acc[i][2] = fmaf(xr[i].y, wc[1].z, acc[i][2]);
            acc[i][3] = fmaf(xr[i].y, wc[1].w, acc[i][3]);
            acc[i][0] = fmaf(xr[i].z, wc[2].x, acc[i][0]);
            acc[i][1] = fmaf(xr[i].z, wc[2].y, acc[i][1]);
            acc[i][2] = fmaf(xr[i].z, wc[2].z, acc[i][2]);
            acc[i][3] = fmaf(xr[i].z, wc[2].w, acc[i][3]);
            acc[i][0] = fmaf(xr[i].w, wc[3].x, acc[i][0]);
            acc[i][1] = fmaf(xr[i].w, wc[3].y, acc[i][1]);
            acc[i][2] = fmaf(xr[i].w, wc[3].z, acc[i][2]);
            acc[i][3] = fmaf(xr[i].w, wc[3].w, acc[i][3]);
        }
    }
    float4 bv = ((const float4*)b)[dg];
#pragma unroll
    for (int i = 0; i < 4; ++i) {
        int node = base + ng * 4 + i;
        if (node < n) {
            ushort4 o;
            o.x = bf16bits(fmaxf(acc[i][0] + bv.x, 0.f));
            o.y = bf16bits(fmaxf(acc[i][1] + bv.y, 0.f));
            o.z = bf16bits(fmaxf(acc[i][2] + bv.z, 0.f));
            o.w = bf16bits(fmaxf(acc[i][3] + bv.w, 0.f));
            out[(size_t)node * 16 + dg] = o;
        }
    }
}

// ---------------- pooling (batch sorted -> run-length partial sums) ----------
#define PCH 256
__global__ __launch_bounds__(256) void k_pool(const int* __restrict__ batch,
                                              const float* __restrict__ h,
                                              float* sums, float* cnt, int n) {
    int t = threadIdx.x;
    int d = t & 63, s = t >> 6;
    int base = blockIdx.x * PCH;
    float acc = 0.f;
    int gcur = -1, cntv = 0;
    for (int i = s; i < PCH; i += 4) {
        int node = base + i;
        if (node >= n) break;
        int g = batch[node];
        if (g != gcur) {
            if (gcur >= 0) {
                atomicAdd(&sums[gcur * DIM + d], acc);
                if (d == 0) atomicAdd(&cnt[gcur], (float)cntv);
            }
            gcur = g;
            acc = 0.f;
            cntv = 0;
        }
        acc += h[(size_t)node * DIM + d];
        cntv++;
    }
    if (gcur >= 0) {
        atomicAdd(&sums[gcur * DIM + d], acc);
        if (d == 0) atomicAdd(&cnt[gcur], (float)cntv);
    }
}

// ---------------- head: mean -> @W2+b2 -> fc1 relu -> fc2 -> out ----------------
__global__ __launch_bounds__(64) void k_head(const float* __restrict__ sums,
                                             const float* __restrict__ cnt,
                                             const float* __restrict__ W2,
                                             const float* __restrict__ b2,
                                             const float* __restrict__ fc1w,
                                             const float* __restrict__ fc1b,
                                             const float* __restrict__ fc2w,
                                             const float* __restrict__ fc2b,
                                             const float* __restrict__ ow,
                                             const float* __restrict__ ob,
                                             float* __restrict__ out) {
    int g = blockIdx.x;
    int t = threadIdx.x;
    __shared__ float gv[64];
    __shared__ float tv[64];
    float c = fmaxf(cnt[g], 1.0f);
    gv[t] = sums[g * DIM + t] / c;
    __syncthreads();
    float acc2 = b2[t];
#pragma unroll
    for (int k = 0; k < 64; ++k) acc2 = fmaf(gv[k], W2[k * 64 + t], acc2);
    tv[t] = acc2;
    __syncthreads();
    float r = 0.0f;
    if (t < 32) {
        float acc = fc1b[t];
#pragma unroll
        for (int k = 0; k < 64; ++k) acc = fmaf(tv[k], fc1w[k * 32 + t], acc);
        acc = fmaxf(acc, 0.0f);
        r = acc * fc2w[t];
    }
#pragma unroll
    for (int off = 16; off; off >>= 1) r += __shfl_down(r, off);
    if (t == 0) out[g] = (r + fc2b[0]) * ow[0] + ob[0];
}

extern "C" void kernel_launch(void* const* d_in, const int* in_sizes, int n_in,
                              void* d_out, int out_size, void* d_ws, size_t ws_size,
                              hipStream_t stream) {
    const float* x   = (const float*)d_in[0];
    const int* eidx  = (const int*)d_in[1];
    const float* ew  = (const float*)d_in[2];
    const int* batch = (const int*)d_in[3];
    const float* W0  = (const float*)d_in[4];
    const float* b0  = (const float*)d_in[5];
    const float* W1  = (const float*)d_in[6];
    const float* b1  = (const float*)d_in[7];
    const float* W2  = (const float*)d_in[8];
    const float* b2  = (const float*)d_in[9];
    const float* fc1w = (const float*)d_in[10];
    const float* fc1b = (const float*)d_in[11];
    const float* fc2w = (const float*)d_in[12];
    const float* fc2b = (const float*)d_in[13];
    const float* ow   = (const float*)d_in[14];
    const float* ob   = (const float*)d_in[15];
    float* out = (float*)d_out;

    const int* row = eidx;
    const int* col = eidx + NE;

    // workspace layout (16B-aligned blocks first)
    char* ws = (char*)d_ws;
    int2* binned           = (int2*)ws;               ws += sizeof(int2) * NE;                 // 12.8MB
    int2* csr              = (int2*)ws;               ws += sizeof(int2) * NE;                 // 12.8MB
    __hip_bfloat16* Xb     = (__hip_bfloat16*)ws;     ws += sizeof(__hip_bfloat16) * (size_t)NN * DIM;
    __hip_bfloat16* Hb     = (__hip_bfloat16*)ws;     ws += sizeof(__hip_bfloat16) * (size_t)NN * DIM;
    float* G               = (float*)ws;              ws += sizeof(float) * (size_t)NN * DIM;  // 25.6MB
    float* dinv            = (float*)ws;              ws += sizeof(float) * NN;
    int*   rowptr          = (int*)ws;                ws += sizeof(int) * (NN + 1);
    int*   gcnt            = (int*)ws;                ws += sizeof(int) * (NBUK + 1);
    int*   boff            = (int*)ws;                ws += sizeof(int) * (NBUK + 1);
    int*   bcur            = (int*)ws;                ws += sizeof(int) * (NBUK + 1);
    float* sums            = (float*)ws;              ws += sizeof(float) * NG * DIM;
    float* cntf            = (float*)ws;              ws += sizeof(float) * NG;

    const int TB = 256;
    int p1_blocks = (NE + EPB - 1) / EPB;  // 391

    // ---- CSR build: block-private bucket reservations (write-merge friendly) ----
    hipMemsetAsync(gcnt, 0, sizeof(int) * NBUK, stream);
    k_ghist<<<p1_blocks, TB, 0, stream>>>(col, gcnt, NE);
    k_gscan<<<1, 256, 0, stream>>>(gcnt, boff, bcur, sums, cntf);
    k_part1<<<p1_blocks, TB, 0, stream>>>(row, col, ew, bcur, binned, NE);
    k_p2a<<<NBUK, 256, 0, stream>>>(binned, boff, dinv, rowptr);
    k_p2b<<<NBUK, 256, 0, stream>>>(binned, boff, dinv, rowptr, csr);

    // cast x -> bf16
    int nq = NN * DIM / 4;
    k_cast<<<(nq + TB - 1) / TB, TB, 0, stream>>>(x, (unsigned short*)Xb, nq);

    int gemm_blocks = (NN + 63) / 64;
    int gath_blocks = (NN + 3) / 4;

    // gather-first layers (bf16 pipeline): g = Ahat@X ; X' = relu(g @ W + b)
    k_gather3<false><<<gath_blocks, 256, 0, stream>>>(rowptr, csr, (const uint4*)Xb, dinv, Hb, NN);
    k_gemm64v3<<<gemm_blocks, 256, 0, stream>>>((const ushort4*)Hb, W0, b0, (ushort4*)Xb, NN);
    k_gather3<false><<<gath_blocks, 256, 0, stream>>>(rowptr, csr, (const uint4*)Xb, dinv, Hb, NN);
    k_gemm64v3<<<gemm_blocks, 256, 0, stream>>>((const ushort4*)Hb, W1, b1, (ushort4*)Xb, NN);
    k_gather3<true><<<gath_blocks, 256, 0, stream>>>(rowptr, csr, (const uint4*)Xb, dinv, G, NN);

    // pool over final gather; W2/b2 folded into head
    k_pool<<<(NN + PCH - 1) / PCH, 256, 0, stream>>>(batch, G, sums, cntf, NN);
    k_head<<<NG, 64, 0, stream>>>(sums, cntf, W2, b2, fc1w, fc1b, fc2w, fc2b, ow, ob, out);
}

// Round 12
// 263.436 us; speedup vs baseline: 3.8348x; 1.1171x over previous
//
#include <hip/hip_runtime.h>
#include <hip/hip_bf16.h>

#define NN 100000
#define NE 1600000
#define DIM 64
#define NG 64

#define NBUK 391      // coarse buckets of 256 nodes: bucket = col >> 8
#define EPB 4096      // edges per pass-1 block

static __device__ __forceinline__ unsigned short bf16bits(float v) {
    __hip_bfloat16 b = __float2bfloat16(v);
    return *reinterpret_cast<unsigned short*>(&b);
}
static __device__ __forceinline__ float bfbits2f(unsigned short u) {
    unsigned int x = ((unsigned int)u) << 16;
    return __uint_as_float(x);
}
// unpack packed bf16x2 dword -> two floats (lo = even dim, hi = odd dim)
static __device__ __forceinline__ void bf2x(unsigned int u, float& lo, float& hi) {
    lo = __uint_as_float(u << 16);
    hi = __uint_as_float(u & 0xFFFF0000u);
}

// ---------------- global bucket histogram (LDS-aggregated) ----------------
__global__ __launch_bounds__(256) void k_ghist(const int* __restrict__ col,
                                               int* gcnt, int E) {
    __shared__ int hist[NBUK];
    int t = threadIdx.x;
    for (int i = t; i < NBUK; i += 256) hist[i] = 0;
    __syncthreads();
    int e0 = blockIdx.x * EPB, e1 = min(e0 + EPB, E);
    for (int e = e0 + t; e < e1; e += 256) atomicAdd(&hist[col[e] >> 8], 1);
    __syncthreads();
    for (int i = t; i < NBUK; i += 256)
        if (hist[i]) atomicAdd(&gcnt[i], hist[i]);
}

// ---------------- bucket offsets scan (one block) + zero pool buffers ----------
__global__ __launch_bounds__(256) void k_gscan(const int* __restrict__ gcnt,
                                               int* __restrict__ boff,
                                               int* __restrict__ bcur,
                                               float* __restrict__ sums,
                                               float* __restrict__ cntf) {
    __shared__ int sm[256];
    int t = threadIdx.x;
    for (int i = t; i < NG * DIM; i += 256) sums[i] = 0.f;
    if (t < NG) cntf[t] = 0.f;
    int v0 = (2 * t < NBUK) ? gcnt[2 * t] : 0;
    int v1 = (2 * t + 1 < NBUK) ? gcnt[2 * t + 1] : 0;
    int s = v0 + v1;
    sm[t] = s;
    __syncthreads();
    for (int off = 1; off < 256; off <<= 1) {
        int tmp = (t >= off) ? sm[t - off] : 0;
        __syncthreads();
        sm[t] += tmp;
        __syncthreads();
    }
    int run = sm[t] - s;
    if (2 * t < NBUK) { boff[2 * t] = run; bcur[2 * t] = run; }
    run += v0;
    if (2 * t + 1 < NBUK) { boff[2 * t + 1] = run; bcur[2 * t + 1] = run; }
    if (t == 255) boff[NBUK] = run + v1;  // == NE
}

// ---------------- pass 1: block-local counting sort into bucket ranges ----------
// binned record: .x = (cl<<17)|row  (cl = col&255, row<2^17), .y = ew bits
__global__ __launch_bounds__(256) void k_part1(const int* __restrict__ row,
                                               const int* __restrict__ col,
                                               const float* __restrict__ ew,
                                               int* bcur, int2* __restrict__ binned,
                                               int E) {
    __shared__ int hist[NBUK];
    __shared__ int base_s[NBUK];
    int t = threadIdx.x;
    for (int i = t; i < NBUK; i += 256) hist[i] = 0;
    __syncthreads();
    int e0 = blockIdx.x * EPB, e1 = min(e0 + EPB, E);
    for (int e = e0 + t; e < e1; e += 256) atomicAdd(&hist[col[e] >> 8], 1);
    __syncthreads();
    for (int i = t; i < NBUK; i += 256) {
        int c = hist[i];
        base_s[i] = c ? atomicAdd(&bcur[i], c) : 0;
        hist[i] = 0;  // reuse as local cursor
    }
    __syncthreads();
    for (int e = e0 + t; e < e1; e += 256) {
        int c = col[e];
        int b = c >> 8, cl = c & 255;
        int rk = atomicAdd(&hist[b], 1);
        binned[base_s[b] + rk] = make_int2((cl << 17) | row[e], __float_as_int(ew[e]));
    }
}

// ---------------- pass 2a: per-bucket degree (fixed-point) + rowptr + dinv --------
__global__ __launch_bounds__(256) void k_p2a(const int2* __restrict__ binned,
                                             const int* __restrict__ boff,
                                             float* __restrict__ dinv,
                                             int* __restrict__ rowptr) {
    int b = blockIdx.x, t = threadIdx.x;
    __shared__ unsigned int dsum[256];
    __shared__ int ncnt[256];
    __shared__ int sm[256];
    dsum[t] = 0;
    ncnt[t] = 0;
    __syncthreads();
    int e0 = boff[b], e1 = boff[b + 1];
    for (int e = e0 + t; e < e1; e += 256) {
        int2 v = binned[e];
        int cl = v.x >> 17;
        atomicAdd(&ncnt[cl], 1);
        unsigned int fx = (unsigned int)__float2uint_rn(__int_as_float(v.y) * 16777216.0f);
        atomicAdd(&dsum[cl], fx);
    }
    __syncthreads();
    int c = ncnt[t];
    sm[t] = c;
    __syncthreads();
    for (int off = 1; off < 256; off <<= 1) {
        int tmp = (t >= off) ? sm[t - off] : 0;
        __syncthreads();
        sm[t] += tmp;
        __syncthreads();
    }
    int node = b * 256 + t;
    if (node < NN) {
        rowptr[node] = e0 + sm[t] - c;
        dinv[node] = rsqrtf(1.0f + (float)dsum[t] * (1.0f / 16777216.0f));
    }
    if (b == 0 && t == 0) rowptr[NN] = NE;
}

// ---------------- pass 2b: per-bucket CSR place (contiguous window) ----------------
__global__ __launch_bounds__(256) void k_p2b(const int2* __restrict__ binned,
                                             const int* __restrict__ boff,
                                             const float* __restrict__ dinv,
                                             const int* __restrict__ rowptr,
                                             int2* __restrict__ csr) {
    int b = blockIdx.x, t = threadIdx.x;
    __shared__ int ncur[256];
    __shared__ float ldin[256];
    int node = b * 256 + t;
    ncur[t] = (node < NN) ? rowptr[node] : 0;
    ldin[t] = (node < NN) ? dinv[node] : 0.f;
    __syncthreads();
    int e0 = boff[b], e1 = boff[b + 1];
    for (int e = e0 + t; e < e1; e += 256) {
        int2 v = binned[e];
        int cl = v.x >> 17, r = v.x & 0x1FFFF;
        float nm = dinv[r] * __int_as_float(v.y) * ldin[cl];
        int p = atomicAdd(&ncur[cl], 1);
        csr[p] = make_int2(r, __float_as_int(nm));
    }
}

// ---------------- cast x -> bf16 ----------------
__global__ void k_cast(const float* __restrict__ x, unsigned short* __restrict__ xb, int nq) {
    int i = blockIdx.x * blockDim.x + threadIdx.x;
    if (i >= nq) return;
    float4 v = ((const float4*)x)[i];
    ushort4 o;
    o.x = bf16bits(v.x);
    o.y = bf16bits(v.y);
    o.z = bf16bits(v.z);
    o.w = bf16bits(v.w);
    ((ushort4*)xb)[i] = o;
}

// ---------------- gather v4: 4 nodes/wave, 2 groups/node, 4-deep csr pipeline ----
// lane layout: node cluster = 16 lanes (tid>>4 within block of 256 -> 16 nodes/block);
// within cluster: g2 = (l>>3)&1 (2 edge groups, stride 2), sub = l&7 (16B chunk).
// 4 independent dep-chains per wave; csr batch i+1 prefetched during batch i.
template <bool F32OUT>
__global__ __launch_bounds__(256) void k_gather4(const int* __restrict__ rowptr,
                                                 const int2* __restrict__ csr,
                                                 const uint4* __restrict__ h8,
                                                 const float* __restrict__ dinv,
                                                 void* __restrict__ out, int n) {
    int tid = threadIdx.x;
    int node = blockIdx.x * 16 + (tid >> 4);
    if (node >= n) return;
    int l = tid & 15;
    int g2 = l >> 3, sub = l & 7;
    float acc[8];
#pragma unroll
    for (int i = 0; i < 8; ++i) acc[i] = 0.f;
    if (g2 == 0) {  // self-loop term (added once per node)
        float di = dinv[node];
        float s = di * di;
        uint4 v = h8[(size_t)node * 8 + sub];
        float lo, hi;
        bf2x(v.x, lo, hi); acc[0] = lo * s; acc[1] = hi * s;
        bf2x(v.y, lo, hi); acc[2] = lo * s; acc[3] = hi * s;
        bf2x(v.z, lo, hi); acc[4] = lo * s; acc[5] = hi * s;
        bf2x(v.w, lo, hi); acc[6] = lo * s; acc[7] = hi * s;
    }
    int e1 = rowptr[node + 1];
    int e = rowptr[node] + g2;
    // prologue: 4-deep csr batch (stride 2 within group)
    int2 p[4];
#pragma unroll
    for (int i = 0; i < 4; ++i) {
        p[i] = make_int2(0, 0);
        if (e + 2 * i < e1) p[i] = csr[e + 2 * i];
    }
    while (e < e1) {
        // issue current batch row loads (guarded: inactive lanes fetch nothing)
        uint4 r[4];
#pragma unroll
        for (int i = 0; i < 4; ++i) {
            r[i] = make_uint4(0u, 0u, 0u, 0u);
            if (e + 2 * i < e1) r[i] = h8[(size_t)p[i].x * 8 + sub];
        }
        // prefetch next csr batch while rows are in flight
        int en = e + 8;
        int2 q[4];
#pragma unroll
        for (int i = 0; i < 4; ++i) {
            q[i] = make_int2(0, 0);
            if (en + 2 * i < e1) q[i] = csr[en + 2 * i];
        }
        // consume rows
#pragma unroll
        for (int i = 0; i < 4; ++i) {
            float nm = __int_as_float(p[i].y);
            float lo, hi;
            bf2x(r[i].x, lo, hi); acc[0] = fmaf(lo, nm, acc[0]); acc[1] = fmaf(hi, nm, acc[1]);
            bf2x(r[i].y, lo, hi); acc[2] = fmaf(lo, nm, acc[2]); acc[3] = fmaf(hi, nm, acc[3]);
            bf2x(r[i].z, lo, hi); acc[4] = fmaf(lo, nm, acc[4]); acc[5] = fmaf(hi, nm, acc[5]);
            bf2x(r[i].w, lo, hi); acc[6] = fmaf(lo, nm, acc[6]); acc[7] = fmaf(hi, nm, acc[7]);
        }
#pragma unroll
        for (int i = 0; i < 4; ++i) p[i] = q[i];
        e = en;
    }
    // merge the 2 groups (lane l <-> l^8, same 16-lane cluster)
#pragma unroll
    for (int i = 0; i < 8; ++i) acc[i] += __shfl_xor(acc[i], 8);
    if (g2 == 0) {
        if (F32OUT) {
            float4 f0 = make_float4(acc[0], acc[1], acc[2], acc[3]);
            float4 f1 = make_float4(acc[4], acc[5], acc[6], acc[7]);
            ((float4*)out)[(size_t)node * 16 + sub * 2 + 0] = f0;
            ((float4*)out)[(size_t)node * 16 + sub * 2 + 1] = f1;
        } else {
            uint4 o;
            o.x = ((unsigned int)bf16bits(acc[1]) << 16) | bf16bits(acc[0]);
            o.y = ((unsigned int)bf16bits(acc[3]) << 16) | bf16bits(acc[2]);
            o.z = ((unsigned int)bf16bits(acc[5]) << 16) | bf16bits(acc[4]);
            o.w = ((unsigned int)bf16bits(acc[7]) << 16) | bf16bits(acc[6]);
            ((uint4*)out)[(size_t)node * 8 + sub] = o;
        }
    }
}

// ---------------- GEMM v3: 64-node tile, 4x4 register tile, register-capped ------
__global__ __launch_bounds__(256, 4) void k_gemm64v3(const ushort4* __restrict__ in,
                                                     const float* __restrict__ W,
                                                     const float* __restrict__ b,
                                                     ushort4* __restrict__ out, int n) {
    __shared__ float sW[64][64];   // [k][d]
    __shared__ float sX[64][68];   // [node][k], +4 pad
    int tid = threadIdx.x;
#pragma unroll
    for (int i = 0; i < 4; ++i) {
        int q = tid + i * 256;
        ((float4*)&sW[0][0])[q] = ((const float4*)W)[q];
    }
    int base = blockIdx.x * 64;
#pragma unroll
    for (int i = 0; i < 4; ++i) {
        int idx = tid + i * 256;  // 0..1023
        int r = idx >> 4, q = idx & 15;
        int node = base + r;
        float4 f = make_float4(0.f, 0.f, 0.f, 0.f);
        if (node < n) {
            ushort4 v = in[(size_t)node * 16 + q];
            f.x = bfbits2f(v.x);
            f.y = bfbits2f(v.y);
            f.z = bfbits2f(v.z);
            f.w = bfbits2f(v.w);
        }
        *(float4*)&sX[r][q * 4] = f;
    }
    __syncthreads();
    int ng = tid >> 4;
    int dg = tid & 15;
    float acc[4][4];
#pragma unroll
    for (int i = 0; i < 4; ++i)
#pragma unroll
        for (int j = 0; j < 4; ++j) acc[i][j] = 0.f;
#pragma unroll 4
    for (int k4 = 0; k4 < 16; ++k4) {
        float4 xr[4];
#pragma unroll
        for (int i = 0; i < 4; ++i) xr[i] = *(const float4*)&sX[ng * 4 + i][k4 * 4];
        float4 wc[4];
#pragma unroll
        for (int j = 0; j < 4; ++j) wc[j] = *(const float4*)&sW[k4 * 4 + j][dg * 4];
#pragma unroll
        for (int i = 0; i < 4; ++i) {
            acc[i][0] = fmaf(xr[i].x, wc[0].x, acc[i][0]);
            acc[i][1] = fmaf(xr[i].x, wc[0].y, acc[i][1]);
            acc[i][2] = fmaf(xr[i].x, wc[0].z, acc[i][2]);
            acc[i][3] = fmaf(xr[i].x, wc[0].w, acc[i][3]);
            acc[i][0] = fmaf(xr[i].y, wc[1].x, acc[i][0]);
            acc[i][1] = fmaf(xr[i].y, wc[1].y, acc[i][1]);
            acc[i][2] = fmaf(xr[i].y, wc[1].z, acc[i][2]);
            acc[i][3] = fmaf(xr[i].y, wc[1].w, acc[i][3]);
            acc[i][0] = fmaf(xr[i].z, wc[2].x, acc[i][0]);
            acc[i][1] = fmaf(xr[i].z, wc[2].y, acc[i][1]);
            acc[i][2] = fmaf(xr[i].z, wc[2].z, acc[i][2]);
            acc[i][3] = fmaf(xr[i].z, wc[2].w, acc[i][3]);
            acc[i][0] = fmaf(xr[i].w, wc[3].x, acc[i][0]);
            acc[i][1] = fmaf(xr[i].w, wc[3].y, acc[i][1]);
            acc[i][2] = fmaf(xr[i].w, wc[3].z, acc[i][2]);
            acc[i][3] = fmaf(xr[i].w, wc[3].w, acc[i][3]);
        }
    }
    float4 bv = ((const float4*)b)[dg];
#pragma unroll
    for (int i = 0; i < 4; ++i) {
        int node = base + ng * 4 + i;
        if (node < n) {
            ushort4 o;
            o.x = bf16bits(fmaxf(acc[i][0] + bv.x, 0.f));
            o.y = bf16bits(fmaxf(acc[i][1] + bv.y, 0.f));
            o.z = bf16bits(fmaxf(acc[i][2] + bv.z, 0.f));
            o.w = bf16bits(fmaxf(acc[i][3] + bv.w, 0.f));
            out[(size_t)node * 16 + dg] = o;
        }
    }
}

// ---------------- pooling (batch sorted -> run-length partial sums) ----------
#define PCH 256
__global__ __launch_bounds__(256) void k_pool(const int* __restrict__ batch,
                                              const float* __restrict__ h,
                                              float* sums, float* cnt, int n) {
    int t = threadIdx.x;
    int d = t & 63, s = t >> 6;
    int base = blockIdx.x * PCH;
    float acc = 0.f;
    int gcur = -1, cntv = 0;
    for (int i = s; i < PCH; i += 4) {
        int node = base + i;
        if (node >= n) break;
        int g = batch[node];
        if (g != gcur) {
            if (gcur >= 0) {
                atomicAdd(&sums[gcur * DIM + d], acc);
                if (d == 0) atomicAdd(&cnt[gcur], (float)cntv);
            }
            gcur = g;
            acc = 0.f;
            cntv = 0;
        }
        acc += h[(size_t)node * DIM + d];
        cntv++;
    }
    if (gcur >= 0) {
        atomicAdd(&sums[gcur * DIM + d], acc);
        if (d == 0) atomicAdd(&cnt[gcur], (float)cntv);
    }
}

// ---------------- head: mean -> @W2+b2 -> fc1 relu -> fc2 -> out ----------------
__global__ __launch_bounds__(64) void k_head(const float* __restrict__ sums,
                                             const float* __restrict__ cnt,
                                             const float* __restrict__ W2,
                                             const float* __restrict__ b2,
                                             const float* __restrict__ fc1w,
                                             const float* __restrict__ fc1b,
                                             const float* __restrict__ fc2w,
                                             const float* __restrict__ fc2b,
                                             const float* __restrict__ ow,
                                             const float* __restrict__ ob,
                                             float* __restrict__ out) {
    int g = blockIdx.x;
    int t = threadIdx.x;
    __shared__ float gv[64];
    __shared__ float tv[64];
    float c = fmaxf(cnt[g], 1.0f);
    gv[t] = sums[g * DIM + t] / c;
    __syncthreads();
    float acc2 = b2[t];
#pragma unroll
    for (int k = 0; k < 64; ++k) acc2 = fmaf(gv[k], W2[k * 64 + t], acc2);
    tv[t] = acc2;
    __syncthreads();
    float r = 0.0f;
    if (t < 32) {
        float acc = fc1b[t];
#pragma unroll
        for (int k = 0; k < 64; ++k) acc = fmaf(tv[k], fc1w[k * 32 + t], acc);
        acc = fmaxf(acc, 0.0f);
        r = acc * fc2w[t];
    }
#pragma unroll
    for (int off = 16; off; off >>= 1) r += __shfl_down(r, off);
    if (t == 0) out[g] = (r + fc2b[0]) * ow[0] + ob[0];
}

extern "C" void kernel_launch(void* const* d_in, const int* in_sizes, int n_in,
                              void* d_out, int out_size, void* d_ws, size_t ws_size,
                              hipStream_t stream) {
    const float* x   = (const float*)d_in[0];
    const int* eidx  = (const int*)d_in[1];
    const float* ew  = (const float*)d_in[2];
    const int* batch = (const int*)d_in[3];
    const float* W0  = (const float*)d_in[4];
    const float* b0  = (const float*)d_in[5];
    const float* W1  = (const float*)d_in[6];
    const float* b1  = (const float*)d_in[7];
    const float* W2  = (const float*)d_in[8];
    const float* b2  = (const float*)d_in[9];
    const float* fc1w = (const float*)d_in[10];
    const float* fc1b = (const float*)d_in[11];
    const float* fc2w = (const float*)d_in[12];
    const float* fc2b = (const float*)d_in[13];
    const float* ow   = (const float*)d_in[14];
    const float* ob   = (const float*)d_in[15];
    float* out = (float*)d_out;

    const int* row = eidx;
    const int* col = eidx + NE;

    // workspace layout (16B-aligned blocks first)
    char* ws = (char*)d_ws;
    int2* binned           = (int2*)ws;               ws += sizeof(int2) * NE;                 // 12.8MB
    int2* csr              = (int2*)ws;               ws += sizeof(int2) * NE;                 // 12.8MB
    __hip_bfloat16* Xb     = (__hip_bfloat16*)ws;     ws += sizeof(__hip_bfloat16) * (size_t)NN * DIM;
    __hip_bfloat16* Hb     = (__hip_bfloat16*)ws;     ws += sizeof(__hip_bfloat16) * (size_t)NN * DIM;
    float* G               = (float*)ws;              ws += sizeof(float) * (size_t)NN * DIM;  // 25.6MB
    float* dinv            = (float*)ws;              ws += sizeof(float) * NN;
    int*   rowptr          = (int*)ws;                ws += sizeof(int) * (NN + 1);
    int*   gcnt            = (int*)ws;                ws += sizeof(int) * (NBUK + 1);
    int*   boff            = (int*)ws;                ws += sizeof(int) * (NBUK + 1);
    int*   bcur            = (int*)ws;                ws += sizeof(int) * (NBUK + 1);
    float* sums            = (float*)ws;              ws += sizeof(float) * NG * DIM;
    float* cntf            = (float*)ws;              ws += sizeof(float) * NG;

    const int TB = 256;
    int p1_blocks = (NE + EPB - 1) / EPB;  // 391

    // ---- CSR build: block-private bucket reservations (write-merge friendly) ----
    hipMemsetAsync(gcnt, 0, sizeof(int) * NBUK, stream);
    k_ghist<<<p1_blocks, TB, 0, stream>>>(col, gcnt, NE);
    k_gscan<<<1, 256, 0, stream>>>(gcnt, boff, bcur, sums, cntf);
    k_part1<<<p1_blocks, TB, 0, stream>>>(row, col, ew, bcur, binned, NE);
    k_p2a<<<NBUK, 256, 0, stream>>>(binned, boff, dinv, rowptr);
    k_p2b<<<NBUK, 256, 0, stream>>>(binned, boff, dinv, rowptr, csr);

    // cast x -> bf16
    int nq = NN * DIM / 4;
    k_cast<<<(nq + TB - 1) / TB, TB, 0, stream>>>(x, (unsigned short*)Xb, nq);

    int gemm_blocks = (NN + 63) / 64;
    int gath_blocks = (NN + 15) / 16;

    // gather-first layers (bf16 pipeline): g = Ahat@X ; X' = relu(g @ W + b)
    k_gather4<false><<<gath_blocks, 256, 0, stream>>>(rowptr, csr, (const uint4*)Xb, dinv, Hb, NN);
    k_gemm64v3<<<gemm_blocks, 256, 0, stream>>>((const ushort4*)Hb, W0, b0, (ushort4*)Xb, NN);
    k_gather4<false><<<gath_blocks, 256, 0, stream>>>(rowptr, csr, (const uint4*)Xb, dinv, Hb, NN);
    k_gemm64v3<<<gemm_blocks, 256, 0, stream>>>((const ushort4*)Hb, W1, b1, (ushort4*)Xb, NN);
    k_gather4<true><<<gath_blocks, 256, 0, stream>>>(rowptr, csr, (const uint4*)Xb, dinv, G, NN);

    // pool over final gather; W2/b2 folded into head
    k_pool<<<(NN + PCH - 1) / PCH, 256, 0, stream>>>(batch, G, sums, cntf, NN);
    k_head<<<NG, 64, 0, stream>>>(sums, cntf, W2, b2, fc1w, fc1b, fc2w, fc2b, ow, ob, out);
}

// Round 13
// 254.906 us; speedup vs baseline: 3.9631x; 1.0335x over previous
//
#include <hip/hip_runtime.h>
#include <hip/hip_bf16.h>

#define NN 100000
#define NE 1600000
#define DIM 64
#define NG 64

#define NBUK 391      // coarse buckets of 256 nodes: bucket = col >> 8
#define EPB 4096      // edges per pass-1 block
#define NBLK 391      // ceil(NE/EPB)

static __device__ __forceinline__ unsigned short bf16bits(float v) {
    __hip_bfloat16 b = __float2bfloat16(v);
    return *reinterpret_cast<unsigned short*>(&b);
}
static __device__ __forceinline__ float bfbits2f(unsigned short u) {
    unsigned int x = ((unsigned int)u) << 16;
    return __uint_as_float(x);
}
// unpack packed bf16x2 dword -> two floats (lo = even dim, hi = odd dim)
static __device__ __forceinline__ void bf2x(unsigned int u, float& lo, float& hi) {
    lo = __uint_as_float(u << 16);
    hi = __uint_as_float(u & 0xFFFF0000u);
}

// ---------------- per-block bucket histogram (persisted) + global counts ----------
__global__ __launch_bounds__(1024) void k_ghist2(const int* __restrict__ col,
                                                 int* __restrict__ hist2d,
                                                 int* gcnt, int E) {
    __shared__ int hist[NBUK];
    int t = threadIdx.x;
    for (int i = t; i < NBUK; i += 1024) hist[i] = 0;
    __syncthreads();
    int e0 = blockIdx.x * EPB, e1 = min(e0 + EPB, E);
    for (int e = e0 + t; e < e1; e += 1024) atomicAdd(&hist[col[e] >> 8], 1);
    __syncthreads();
    for (int i = t; i < NBUK; i += 1024) {
        int c = hist[i];
        hist2d[blockIdx.x * NBUK + i] = c;
        if (c) atomicAdd(&gcnt[i], c);
    }
}

// ---------------- bucket offsets scan (one block) + zero pool buffers ----------
__global__ __launch_bounds__(256) void k_gscan(const int* __restrict__ gcnt,
                                               int* __restrict__ boff,
                                               float* __restrict__ sums,
                                               float* __restrict__ cntf) {
    __shared__ int sm[256];
    int t = threadIdx.x;
    for (int i = t; i < NG * DIM; i += 256) sums[i] = 0.f;
    if (t < NG) cntf[t] = 0.f;
    int v0 = (2 * t < NBUK) ? gcnt[2 * t] : 0;
    int v1 = (2 * t + 1 < NBUK) ? gcnt[2 * t + 1] : 0;
    int s = v0 + v1;
    sm[t] = s;
    __syncthreads();
    for (int off = 1; off < 256; off <<= 1) {
        int tmp = (t >= off) ? sm[t - off] : 0;
        __syncthreads();
        sm[t] += tmp;
        __syncthreads();
    }
    int run = sm[t] - s;
    if (2 * t < NBUK) boff[2 * t] = run;
    run += v0;
    if (2 * t + 1 < NBUK) boff[2 * t + 1] = run;
    if (t == 255) boff[NBUK] = run + v1;  // == NE
}

// ---------------- per-(block,bucket) base: scan hist2d column over blocks --------
__global__ __launch_bounds__(256) void k_colscan(const int* __restrict__ hist2d,
                                                 const int* __restrict__ boff,
                                                 int* __restrict__ base2d) {
    __shared__ int sm[256];
    int b = blockIdx.x, t = threadIdx.x;
    int v0 = (2 * t < NBLK) ? hist2d[(size_t)(2 * t) * NBUK + b] : 0;
    int v1 = (2 * t + 1 < NBLK) ? hist2d[(size_t)(2 * t + 1) * NBUK + b] : 0;
    int s = v0 + v1;
    sm[t] = s;
    __syncthreads();
    for (int off = 1; off < 256; off <<= 1) {
        int tmp = (t >= off) ? sm[t - off] : 0;
        __syncthreads();
        sm[t] += tmp;
        __syncthreads();
    }
    int run = boff[b] + sm[t] - s;
    if (2 * t < NBLK) base2d[(size_t)(2 * t) * NBUK + b] = run;
    run += v0;
    if (2 * t + 1 < NBLK) base2d[(size_t)(2 * t + 1) * NBUK + b] = run;
}

// ---------------- pass 1 v2: single pass, precomputed bases, no global atomics ----
// binned record: .x = (cl<<17)|row  (cl = col&255, row<2^17), .y = ew bits
__global__ __launch_bounds__(1024) void k_part1v2(const int* __restrict__ row,
                                                  const int* __restrict__ col,
                                                  const float* __restrict__ ew,
                                                  const int* __restrict__ base2d,
                                                  int2* __restrict__ binned, int E) {
    __shared__ int cur[NBUK];
    int t = threadIdx.x;
    for (int i = t; i < NBUK; i += 1024) cur[i] = base2d[(size_t)blockIdx.x * NBUK + i];
    __syncthreads();
    int e0 = blockIdx.x * EPB, e1 = min(e0 + EPB, E);
    for (int e = e0 + t; e < e1; e += 1024) {
        int c = col[e];
        int b = c >> 8, cl = c & 255;
        int p = atomicAdd(&cur[b], 1);
        binned[p] = make_int2((cl << 17) | row[e], __float_as_int(ew[e]));
    }
}

// ---------------- pass 2a: per-bucket degree (fixed-point) + rowptr + dinv --------
__global__ __launch_bounds__(256) void k_p2a(const int2* __restrict__ binned,
                                             const int* __restrict__ boff,
                                             float* __restrict__ dinv,
                                             int* __restrict__ rowptr) {
    int b = blockIdx.x, t = threadIdx.x;
    __shared__ unsigned int dsum[256];
    __shared__ int ncnt[256];
    __shared__ int sm[256];
    dsum[t] = 0;
    ncnt[t] = 0;
    __syncthreads();
    int e0 = boff[b], e1 = boff[b + 1];
    for (int e = e0 + t; e < e1; e += 256) {
        int2 v = binned[e];
        int cl = v.x >> 17;
        atomicAdd(&ncnt[cl], 1);
        unsigned int fx = (unsigned int)__float2uint_rn(__int_as_float(v.y) * 16777216.0f);
        atomicAdd(&dsum[cl], fx);
    }
    __syncthreads();
    int c = ncnt[t];
    sm[t] = c;
    __syncthreads();
    for (int off = 1; off < 256; off <<= 1) {
        int tmp = (t >= off) ? sm[t - off] : 0;
        __syncthreads();
        sm[t] += tmp;
        __syncthreads();
    }
    int node = b * 256 + t;
    if (node < NN) {
        rowptr[node] = e0 + sm[t] - c;
        dinv[node] = rsqrtf(1.0f + (float)dsum[t] * (1.0f / 16777216.0f));
    }
    if (b == 0 && t == 0) rowptr[NN] = NE;
}

// ---------------- pass 2b: per-bucket CSR place (contiguous window) ----------------
__global__ __launch_bounds__(256) void k_p2b(const int2* __restrict__ binned,
                                             const int* __restrict__ boff,
                                             const float* __restrict__ dinv,
                                             const int* __restrict__ rowptr,
                                             int2* __restrict__ csr) {
    int b = blockIdx.x, t = threadIdx.x;
    __shared__ int ncur[256];
    __shared__ float ldin[256];
    int node = b * 256 + t;
    ncur[t] = (node < NN) ? rowptr[node] : 0;
    ldin[t] = (node < NN) ? dinv[node] : 0.f;
    __syncthreads();
    int e0 = boff[b], e1 = boff[b + 1];
    for (int e = e0 + t; e < e1; e += 256) {
        int2 v = binned[e];
        int cl = v.x >> 17, r = v.x & 0x1FFFF;
        float nm = dinv[r] * __int_as_float(v.y) * ldin[cl];
        int p = atomicAdd(&ncur[cl], 1);
        csr[p] = make_int2(r, __float_as_int(nm));
    }
}

// ---------------- cast x -> bf16 ----------------
__global__ void k_cast(const float* __restrict__ x, unsigned short* __restrict__ xb, int nq) {
    int i = blockIdx.x * blockDim.x + threadIdx.x;
    if (i >= nq) return;
    float4 v = ((const float4*)x)[i];
    ushort4 o;
    o.x = bf16bits(v.x);
    o.y = bf16bits(v.y);
    o.z = bf16bits(v.z);
    o.w = bf16bits(v.w);
    ((ushort4*)xb)[i] = o;
}

// ---------------- gather v4: 4 nodes/wave, 2 groups/node, 4-deep csr pipeline ----
template <bool F32OUT>
__global__ __launch_bounds__(256) void k_gather4(const int* __restrict__ rowptr,
                                                 const int2* __restrict__ csr,
                                                 const uint4* __restrict__ h8,
                                                 const float* __restrict__ dinv,
                                                 void* __restrict__ out, int n) {
    int tid = threadIdx.x;
    int node = blockIdx.x * 16 + (tid >> 4);
    if (node >= n) return;
    int l = tid & 15;
    int g2 = l >> 3, sub = l & 7;
    float acc[8];
#pragma unroll
    for (int i = 0; i < 8; ++i) acc[i] = 0.f;
    if (g2 == 0) {  // self-loop term (added once per node)
        float di = dinv[node];
        float s = di * di;
        uint4 v = h8[(size_t)node * 8 + sub];
        float lo, hi;
        bf2x(v.x, lo, hi); acc[0] = lo * s; acc[1] = hi * s;
        bf2x(v.y, lo, hi); acc[2] = lo * s; acc[3] = hi * s;
        bf2x(v.z, lo, hi); acc[4] = lo * s; acc[5] = hi * s;
        bf2x(v.w, lo, hi); acc[6] = lo * s; acc[7] = hi * s;
    }
    int e1 = rowptr[node + 1];
    int e = rowptr[node] + g2;
    int2 p[4];
#pragma unroll
    for (int i = 0; i < 4; ++i) {
        p[i] = make_int2(0, 0);
        if (e + 2 * i < e1) p[i] = csr[e + 2 * i];
    }
    while (e < e1) {
        uint4 r[4];
#pragma unroll
        for (int i = 0; i < 4; ++i) {
            r[i] = make_uint4(0u, 0u, 0u, 0u);
            if (e + 2 * i < e1) r[i] = h8[(size_t)p[i].x * 8 + sub];
        }
        int en = e + 8;
        int2 q[4];
#pragma unroll
        for (int i = 0; i < 4; ++i) {
            q[i] = make_int2(0, 0);
            if (en + 2 * i < e1) q[i] = csr[en + 2 * i];
        }
#pragma unroll
        for (int i = 0; i < 4; ++i) {
            float nm = __int_as_float(p[i].y);
            float lo, hi;
            bf2x(r[i].x, lo, hi); acc[0] = fmaf(lo, nm, acc[0]); acc[1] = fmaf(hi, nm, acc[1]);
            bf2x(r[i].y, lo, hi); acc[2] = fmaf(lo, nm, acc[2]); acc[3] = fmaf(hi, nm, acc[3]);
            bf2x(r[i].z, lo, hi); acc[4] = fmaf(lo, nm, acc[4]); acc[5] = fmaf(hi, nm, acc[5]);
            bf2x(r[i].w, lo, hi); acc[6] = fmaf(lo, nm, acc[6]); acc[7] = fmaf(hi, nm, acc[7]);
        }
#pragma unroll
        for (int i = 0; i < 4; ++i) p[i] = q[i];
        e = en;
    }
#pragma unroll
    for (int i = 0; i < 8; ++i) acc[i] += __shfl_xor(acc[i], 8);
    if (g2 == 0) {
        if (F32OUT) {
            float4 f0 = make_float4(acc[0], acc[1], acc[2], acc[3]);
            float4 f1 = make_float4(acc[4], acc[5], acc[6], acc[7]);
            ((float4*)out)[(size_t)node * 16 + sub * 2 + 0] = f0;
            ((float4*)out)[(size_t)node * 16 + sub * 2 + 1] = f1;
        } else {
            uint4 o;
            o.x = ((unsigned int)bf16bits(acc[1]) << 16) | bf16bits(acc[0]);
            o.y = ((unsigned int)bf16bits(acc[3]) << 16) | bf16bits(acc[2]);
            o.z = ((unsigned int)bf16bits(acc[5]) << 16) | bf16bits(acc[4]);
            o.w = ((unsigned int)bf16bits(acc[7]) << 16) | bf16bits(acc[6]);
            ((uint4*)out)[(size_t)node * 8 + sub] = o;
        }
    }
}

// ---------------- GEMM v3: 64-node tile, 4x4 register tile, register-capped ------
__global__ __launch_bounds__(256, 4) void k_gemm64v3(const ushort4* __restrict__ in,
                                                     const float* __restrict__ W,
                                                     const float* __restrict__ b,
                                                     ushort4* __restrict__ out, int n) {
    __shared__ float sW[64][64];   // [k][d]
    __shared__ float sX[64][68];   // [node][k], +4 pad
    int tid = threadIdx.x;
#pragma unroll
    for (int i = 0; i < 4; ++i) {
        int q = tid + i * 256;
        ((float4*)&sW[0][0])[q] = ((const float4*)W)[q];
    }
    int base = blockIdx.x * 64;
#pragma unroll
    for (int i = 0; i < 4; ++i) {
        int idx = tid + i * 256;  // 0..1023
        int r = idx >> 4, q = idx & 15;
        int node = base + r;
        float4 f = make_float4(0.f, 0.f, 0.f, 0.f);
        if (node < n) {
            ushort4 v = in[(size_t)node * 16 + q];
            f.x = bfbits2f(v.x);
            f.y = bfbits2f(v.y);
            f.z = bfbits2f(v.z);
            f.w = bfbits2f(v.w);
        }
        *(float4*)&sX[r][q * 4] = f;
    }
    __syncthreads();
    int ng = tid >> 4;
    int dg = tid & 15;
    float acc[4][4];
#pragma unroll
    for (int i = 0; i < 4; ++i)
#pragma unroll
        for (int j = 0; j < 4; ++j) acc[i][j] = 0.f;
#pragma unroll 4
    for (int k4 = 0; k4 < 16; ++k4) {
        float4 xr[4];
#pragma unroll
        for (int i = 0; i < 4; ++i) xr[i] = *(const float4*)&sX[ng * 4 + i][k4 * 4];
        float4 wc[4];
#pragma unroll
        for (int j = 0; j < 4; ++j) wc[j] = *(const float4*)&sW[k4 * 4 + j][dg * 4];
#pragma unroll
        for (int i = 0; i < 4; ++i) {
            acc[i][0] = fmaf(xr[i].x, wc[0].x, acc[i][0]);
            acc[i][1] = fmaf(xr[i].x, wc[0].y, acc[i][1]);
            acc[i][2] = fmaf(xr[i].x, wc[0].z, acc[i][2]);
            acc[i][3] = fmaf(xr[i].x, wc[0].w, acc[i][3]);
            acc[i][0] = fmaf(xr[i].y, wc[1].x, acc[i][0]);
            acc[i][1] = fmaf(xr[i].y, wc[1].y, acc[i][1]);
            acc[i][2] = fmaf(xr[i].y, wc[1].z, acc[i][2]);
            acc[i][3] = fmaf(xr[i].y, wc[1].w, acc[i][3]);
            acc[i][0] = fmaf(xr[i].z, wc[2].x, acc[i][0]);
            acc[i][1] = fmaf(xr[i].z, wc[2].y, acc[i][1]);
            acc[i][2] = fmaf(xr[i].z, wc[2].z, acc[i][2]);
            acc[i][3] = fmaf(xr[i].z, wc[2].w, acc[i][3]);
            acc[i][0] = fmaf(xr[i].w, wc[3].x, acc[i][0]);
            acc[i][1] = fmaf(xr[i].w, wc[3].y, acc[i][1]);
            acc[i][2] = fmaf(xr[i].w, wc[3].z, acc[i][2]);
            acc[i][3] = fmaf(xr[i].w, wc[3].w, acc[i][3]);
        }
    }
    float4 bv = ((const float4*)b)[dg];
#pragma unroll
    for (int i = 0; i < 4; ++i) {
        int node = base + ng * 4 + i;
        if (node < n) {
            ushort4 o;
            o.x = bf16bits(fmaxf(acc[i][0] + bv.x, 0.f));
            o.y = bf16bits(fmaxf(acc[i][1] + bv.y, 0.f));
            o.z = bf16bits(fmaxf(acc[i][2] + bv.z, 0.f));
            o.w = bf16bits(fmaxf(acc[i][3] + bv.w, 0.f));
            out[(size_t)node * 16 + dg] = o;
        }
    }
}

// ---------------- pooling (batch sorted -> run-length partial sums) ----------
#define PCH 256
__global__ __launch_bounds__(256) void k_pool(const int* __restrict__ batch,
                                              const float* __restrict__ h,
                                              float* sums, float* cnt, int n) {
    int t = threadIdx.x;
    int d = t & 63, s = t >> 6;
    int base = blockIdx.x * PCH;
    float acc = 0.f;
    int gcur = -1, cntv = 0;
    for (int i = s; i < PCH; i += 4) {
        int node = base + i;
        if (node >= n) break;
        int g = batch[node];
        if (g != gcur) {
            if (gcur >= 0) {
                atomicAdd(&sums[gcur * DIM + d], acc);
                if (d == 0) atomicAdd(&cnt[gcur], (float)cntv);
            }
            gcur = g;
            acc = 0.f;
            cntv = 0;
        }
        acc += h[(size_t)node * DIM + d];
        cntv++;
    }
    if (gcur >= 0) {
        atomicAdd(&sums[gcur * DIM + d], acc);
        if (d == 0) atomicAdd(&cnt[gcur], (float)cntv);
    }
}

// ---------------- head: mean -> @W2+b2 -> fc1 relu -> fc2 -> out ----------------
__global__ __launch_bounds__(64) void k_head(const float* __restrict__ sums,
                                             const float* __restrict__ cnt,
                                             const float* __restrict__ W2,
                                             const float* __restrict__ b2,
                                             const float* __restrict__ fc1w,
                                             const float* __restrict__ fc1b,
                                             const float* __restrict__ fc2w,
                                             const float* __restrict__ fc2b,
                                             const float* __restrict__ ow,
                                             const float* __restrict__ ob,
                                             float* __restrict__ out) {
    int g = blockIdx.x;
    int t = threadIdx.x;
    __shared__ float gv[64];
    __shared__ float tv[64];
    float c = fmaxf(cnt[g], 1.0f);
    gv[t] = sums[g * DIM + t] / c;
    __syncthreads();
    float acc2 = b2[t];
#pragma unroll
    for (int k = 0; k < 64; ++k) acc2 = fmaf(gv[k], W2[k * 64 + t], acc2);
    tv[t] = acc2;
    __syncthreads();
    float r = 0.0f;
    if (t < 32) {
        float acc = fc1b[t];
#pragma unroll
        for (int k = 0; k < 64; ++k) acc = fmaf(tv[k], fc1w[k * 32 + t], acc);
        acc = fmaxf(acc, 0.0f);
        r = acc * fc2w[t];
    }
#pragma unroll
    for (int off = 16; off; off >>= 1) r += __shfl_down(r, off);
    if (t == 0) out[g] = (r + fc2b[0]) * ow[0] + ob[0];
}

extern "C" void kernel_launch(void* const* d_in, const int* in_sizes, int n_in,
                              void* d_out, int out_size, void* d_ws, size_t ws_size,
                              hipStream_t stream) {
    const float* x   = (const float*)d_in[0];
    const int* eidx  = (const int*)d_in[1];
    const float* ew  = (const float*)d_in[2];
    const int* batch = (const int*)d_in[3];
    const float* W0  = (const float*)d_in[4];
    const float* b0  = (const float*)d_in[5];
    const float* W1  = (const float*)d_in[6];
    const float* b1  = (const float*)d_in[7];
    const float* W2  = (const float*)d_in[8];
    const float* b2  = (const float*)d_in[9];
    const float* fc1w = (const float*)d_in[10];
    const float* fc1b = (const float*)d_in[11];
    const float* fc2w = (const float*)d_in[12];
    const float* fc2b = (const float*)d_in[13];
    const float* ow   = (const float*)d_in[14];
    const float* ob   = (const float*)d_in[15];
    float* out = (float*)d_out;

    const int* row = eidx;
    const int* col = eidx + NE;

    // workspace layout (16B-aligned blocks first)
    char* ws = (char*)d_ws;
    int2* binned           = (int2*)ws;               ws += sizeof(int2) * NE;                 // 12.8MB
    int2* csr              = (int2*)ws;               ws += sizeof(int2) * NE;                 // 12.8MB
    __hip_bfloat16* Xb     = (__hip_bfloat16*)ws;     ws += sizeof(__hip_bfloat16) * (size_t)NN * DIM;
    __hip_bfloat16* Hb     = (__hip_bfloat16*)ws;     ws += sizeof(__hip_bfloat16) * (size_t)NN * DIM;
    float* G               = (float*)ws;              ws += sizeof(float) * (size_t)NN * DIM;  // 25.6MB
    int*   hist2d          = (int*)ws;                ws += sizeof(int) * (size_t)NBLK * NBUK; // 611KB
    int*   base2d          = (int*)ws;                ws += sizeof(int) * (size_t)NBLK * NBUK; // 611KB
    float* dinv            = (float*)ws;              ws += sizeof(float) * NN;
    int*   rowptr          = (int*)ws;                ws += sizeof(int) * (NN + 1);
    int*   gcnt            = (int*)ws;                ws += sizeof(int) * (NBUK + 1);
    int*   boff            = (int*)ws;                ws += sizeof(int) * (NBUK + 1);
    float* sums            = (float*)ws;              ws += sizeof(float) * NG * DIM;
    float* cntf            = (float*)ws;              ws += sizeof(float) * NG;

    const int TB = 256;

    // ---- CSR build: persisted per-block hists + deterministic bases ----
    hipMemsetAsync(gcnt, 0, sizeof(int) * NBUK, stream);
    k_ghist2<<<NBLK, 1024, 0, stream>>>(col, hist2d, gcnt, NE);
    k_gscan<<<1, 256, 0, stream>>>(gcnt, boff, sums, cntf);
    k_colscan<<<NBUK, 256, 0, stream>>>(hist2d, boff, base2d);
    k_part1v2<<<NBLK, 1024, 0, stream>>>(row, col, ew, base2d, binned, NE);
    k_p2a<<<NBUK, 256, 0, stream>>>(binned, boff, dinv, rowptr);
    k_p2b<<<NBUK, 256, 0, stream>>>(binned, boff, dinv, rowptr, csr);

    // cast x -> bf16
    int nq = NN * DIM / 4;
    k_cast<<<(nq + TB - 1) / TB, TB, 0, stream>>>(x, (unsigned short*)Xb, nq);

    int gemm_blocks = (NN + 63) / 64;
    int gath_blocks = (NN + 15) / 16;

    // gather-first layers (bf16 pipeline): g = Ahat@X ; X' = relu(g @ W + b)
    k_gather4<false><<<gath_blocks, 256, 0, stream>>>(rowptr, csr, (const uint4*)Xb, dinv, Hb, NN);
    k_gemm64v3<<<gemm_blocks, 256, 0, stream>>>((const ushort4*)Hb, W0, b0, (ushort4*)Xb, NN);
    k_gather4<false><<<gath_blocks, 256, 0, stream>>>(rowptr, csr, (const uint4*)Xb, dinv, Hb, NN);
    k_gemm64v3<<<gemm_blocks, 256, 0, stream>>>((const ushort4*)Hb, W1, b1, (ushort4*)Xb, NN);
    k_gather4<true><<<gath_blocks, 256, 0, stream>>>(rowptr, csr, (const uint4*)Xb, dinv, G, NN);

    // pool over final gather; W2/b2 folded into head
    k_pool<<<(NN + PCH - 1) / PCH, 256, 0, stream>>>(batch, G, sums, cntf, NN);
    k_head<<<NG, 64, 0, stream>>>(sums, cntf, W2, b2, fc1w, fc1b, fc2w, fc2b, ow, ob, out);
}